// Round 1
// baseline (1237.977 us; speedup 1.0000x reference)
//
#include <hip/hip_runtime.h>

#define WAVE 64
#define LRELU(x) ((x) > 0.0f ? (x) : 0.2f * (x))

// ---------------- GEMM: C[M,N] = A[M,K] @ B[K,N], fp32, N multiple of 64, K multiple of 16
// 64x64 tile, BK=16, 256 threads, 4x4 micro-tile per thread.
__global__ __launch_bounds__(256) void k_gemm(const float* __restrict__ A,
                                              const float* __restrict__ B,
                                              float* __restrict__ C,
                                              int M, int K, int N) {
    __shared__ float As[16][64];  // [k][m]
    __shared__ float Bs[16][64];  // [k][n]
    const int tid = threadIdx.x;
    const int row0 = blockIdx.y * 64;
    const int col0 = blockIdx.x * 64;
    const int tx = tid & 15;       // micro col group
    const int ty = tid >> 4;       // micro row group
    const int a_m = tid >> 2;            // 0..63
    const int a_k = (tid & 3) * 4;       // 0,4,8,12
    const int b_k = tid >> 4;            // 0..15
    const int b_n = (tid & 15) * 4;      // 0..60

    float acc[4][4];
#pragma unroll
    for (int i = 0; i < 4; i++)
#pragma unroll
        for (int j = 0; j < 4; j++) acc[i][j] = 0.0f;

    for (int k0 = 0; k0 < K; k0 += 16) {
        // stage A tile (transposed into LDS)
        float4 av;
        int arow = row0 + a_m;
        if (arow < M) av = *(const float4*)&A[(size_t)arow * K + k0 + a_k];
        else av = make_float4(0.f, 0.f, 0.f, 0.f);
        As[a_k + 0][a_m] = av.x;
        As[a_k + 1][a_m] = av.y;
        As[a_k + 2][a_m] = av.z;
        As[a_k + 3][a_m] = av.w;
        // stage B tile
        float4 bv = *(const float4*)&B[(size_t)(k0 + b_k) * N + col0 + b_n];
        *(float4*)&Bs[b_k][b_n] = bv;
        __syncthreads();
#pragma unroll
        for (int kk = 0; kk < 16; kk++) {
            float4 a4 = *(const float4*)&As[kk][ty * 4];
            float4 b4 = *(const float4*)&Bs[kk][tx * 4];
            float am[4] = {a4.x, a4.y, a4.z, a4.w};
            float bm[4] = {b4.x, b4.y, b4.z, b4.w};
#pragma unroll
            for (int i = 0; i < 4; i++)
#pragma unroll
                for (int j = 0; j < 4; j++) acc[i][j] = fmaf(am[i], bm[j], acc[i][j]);
        }
        __syncthreads();
    }
#pragma unroll
    for (int i = 0; i < 4; i++) {
        int row = row0 + ty * 4 + i;
        if (row < M) {
            float4 o = make_float4(acc[i][0], acc[i][1], acc[i][2], acc[i][3]);
            *(float4*)&C[(size_t)row * N + col0 + tx * 4] = o;
        }
    }
}

// ---------------- per-node dot products: asrc[i] = h[i,:].as, adst[i] = h[i,:].ad
__global__ __launch_bounds__(256) void k_att(const float* __restrict__ h,
                                             const float* __restrict__ att_s,
                                             const float* __restrict__ att_d,
                                             float* __restrict__ asrc,
                                             float* __restrict__ adst, int N) {
    int wid = threadIdx.x >> 6;
    int lane = threadIdx.x & 63;
    int node = blockIdx.x * 4 + wid;
    if (node >= N) return;
    float4 hv = *(const float4*)&h[(size_t)node * 256 + lane * 4];
    float4 sv = *(const float4*)&att_s[lane * 4];
    float4 dv = *(const float4*)&att_d[lane * 4];
    float s = hv.x * sv.x + hv.y * sv.y + hv.z * sv.z + hv.w * sv.w;
    float d = hv.x * dv.x + hv.y * dv.y + hv.z * dv.z + hv.w * dv.w;
#pragma unroll
    for (int off = 32; off; off >>= 1) {
        s += __shfl_xor(s, off);
        d += __shfl_xor(d, off);
    }
    if (lane == 0) { asrc[node] = s; adst[node] = d; }
}

// ---------------- gate[i] = h[i,:].gw + gb
__global__ __launch_bounds__(256) void k_gate(const float* __restrict__ h,
                                              const float* __restrict__ gw,
                                              const float* __restrict__ gb,
                                              float* __restrict__ gate, int N) {
    int wid = threadIdx.x >> 6;
    int lane = threadIdx.x & 63;
    int node = blockIdx.x * 4 + wid;
    if (node >= N) return;
    float4 hv = *(const float4*)&h[(size_t)node * 256 + lane * 4];
    float4 gv = *(const float4*)&gw[lane * 4];
    float s = hv.x * gv.x + hv.y * gv.y + hv.z * gv.z + hv.w * gv.w;
#pragma unroll
    for (int off = 32; off; off >>= 1) s += __shfl_xor(s, off);
    if (lane == 0) gate[node] = s + gb[0];
}

// ---------------- CSR build
__global__ __launch_bounds__(256) void k_degree(const int* __restrict__ dst,
                                                int* __restrict__ counts, int E) {
    int e = blockIdx.x * 256 + threadIdx.x;
    if (e < E) atomicAdd(&counts[dst[e]], 1);
}

__global__ __launch_bounds__(256) void k_scan(const int* __restrict__ counts,
                                              int* __restrict__ rowptr,
                                              int* __restrict__ cursor, int N) {
    __shared__ int sscan[256];
    int tid = threadIdx.x;
    int running = 0;
    for (int base = 0; base < N; base += 256) {
        int i = base + tid;
        int v = (i < N) ? counts[i] : 0;
        sscan[tid] = v;
        __syncthreads();
        for (int off = 1; off < 256; off <<= 1) {
            int t = (tid >= off) ? sscan[tid - off] : 0;
            __syncthreads();
            sscan[tid] += t;
            __syncthreads();
        }
        int excl = running + sscan[tid] - v;
        if (i < N) { rowptr[i] = excl; cursor[i] = excl; }
        running += sscan[255];
        __syncthreads();
    }
    if (tid == 0) rowptr[N] = running;
}

__global__ __launch_bounds__(256) void k_scatter(const int* __restrict__ src,
                                                 const int* __restrict__ dst,
                                                 int* __restrict__ cursor,
                                                 int* __restrict__ col, int E) {
    int e = blockIdx.x * 256 + threadIdx.x;
    if (e < E) {
        int p = atomicAdd(&cursor[dst[e]], 1);
        col[p] = src[e];
    }
}

// ---------------- GAT aggregation: per node (wave), softmax over incoming edges + self loop,
// out[i,:] = relu( sum_j alpha_j * h[src_j,:] + bias )
__global__ __launch_bounds__(256) void k_agg(const float* __restrict__ h,
                                             const float* __restrict__ asrc,
                                             const float* __restrict__ adst,
                                             const int* __restrict__ rowptr,
                                             const int* __restrict__ col,
                                             const float* __restrict__ bias,
                                             float* __restrict__ out, int N) {
    int wid = threadIdx.x >> 6;
    int lane = threadIdx.x & 63;
    int node = blockIdx.x * 4 + wid;
    if (node >= N) return;
    int start = rowptr[node];
    int end = rowptr[node + 1];
    float ad = adst[node];
    // pass 1: max score (self loop + incoming edges)
    float eself = asrc[node] + ad;
    eself = LRELU(eself);
    float m = eself;
    for (int j = start + lane; j < end; j += WAVE) {
        float e = asrc[col[j]] + ad;
        e = LRELU(e);
        m = fmaxf(m, e);
    }
#pragma unroll
    for (int off = 32; off; off >>= 1) m = fmaxf(m, __shfl_xor(m, off));
    // pass 2: weighted accumulate
    float denom = 0.0f;
    float ax = 0.f, ay = 0.f, az = 0.f, aw = 0.f;
    {
        float w = __expf(eself - m);
        denom += w;
        float4 hv = *(const float4*)&h[(size_t)node * 256 + lane * 4];
        ax = fmaf(w, hv.x, ax); ay = fmaf(w, hv.y, ay);
        az = fmaf(w, hv.z, az); aw = fmaf(w, hv.w, aw);
    }
    for (int j = start; j < end; j++) {
        int s = col[j];
        float e = asrc[s] + ad;
        e = LRELU(e);
        float w = __expf(e - m);
        denom += w;
        float4 hv = *(const float4*)&h[(size_t)s * 256 + lane * 4];
        ax = fmaf(w, hv.x, ax); ay = fmaf(w, hv.y, ay);
        az = fmaf(w, hv.z, az); aw = fmaf(w, hv.w, aw);
    }
    float inv = 1.0f / (denom + 1e-16f);
    float4 bv = *(const float4*)&bias[lane * 4];
    float4 o;
    o.x = fmaxf(ax * inv + bv.x, 0.0f);
    o.y = fmaxf(ay * inv + bv.y, 0.0f);
    o.z = fmaxf(az * inv + bv.z, 0.0f);
    o.w = fmaxf(aw * inv + bv.w, 0.0f);
    *(float4*)&out[(size_t)node * 256 + lane * 4] = o;
}

// ---------------- global attention reductions (single block): gmax, gsum; zero gout
__global__ __launch_bounds__(256) void k_gred(const float* __restrict__ gate, int N,
                                              float* __restrict__ scal,
                                              float* __restrict__ gout) {
    __shared__ float red[256];
    int tid = threadIdx.x;
    float m = -3.0e38f;
    for (int i = tid; i < N; i += 256) m = fmaxf(m, gate[i]);
    red[tid] = m;
    __syncthreads();
    for (int off = 128; off; off >>= 1) {
        if (tid < off) red[tid] = fmaxf(red[tid], red[tid + off]);
        __syncthreads();
    }
    float gmax = red[0];
    __syncthreads();
    float s = 0.0f;
    for (int i = tid; i < N; i += 256) s += __expf(gate[i] - gmax);
    red[tid] = s;
    __syncthreads();
    for (int off = 128; off; off >>= 1) {
        if (tid < off) red[tid] += red[tid + off];
        __syncthreads();
    }
    if (tid == 0) { scal[0] = gmax; scal[1] = red[0]; }
    gout[tid] = 0.0f;
}

// ---------------- weighted feature sum: gout[f] += sum_i exp(gate[i]-gmax) * h[i,f]
__global__ __launch_bounds__(256) void k_gout(const float* __restrict__ h,
                                              const float* __restrict__ gate,
                                              const float* __restrict__ scal,
                                              float* __restrict__ gout, int N) {
    int f = threadIdx.x;
    float gmax = scal[0];
    float acc = 0.0f;
    for (int i = blockIdx.x; i < N; i += gridDim.x) {
        float w = __expf(gate[i] - gmax);
        acc = fmaf(w, h[(size_t)i * 256 + f], acc);
    }
    atomicAdd(&gout[f], acc);
}

__global__ __launch_bounds__(256) void k_final(const float* __restrict__ gout,
                                               const float* __restrict__ scal,
                                               float* __restrict__ out) {
    int f = threadIdx.x;
    out[f] = gout[f] / scal[1];
}

extern "C" void kernel_launch(void* const* d_in, const int* in_sizes, int n_in,
                              void* d_out, int out_size, void* d_ws, size_t ws_size,
                              hipStream_t stream) {
    const float* x   = (const float*)d_in[0];
    const int*   ei  = (const int*)d_in[1];
    const float* W1  = (const float*)d_in[2];
    const float* b1  = (const float*)d_in[3];
    const float* as1 = (const float*)d_in[4];
    const float* ad1 = (const float*)d_in[5];
    const float* W2  = (const float*)d_in[6];
    const float* b2  = (const float*)d_in[7];
    const float* as2 = (const float*)d_in[8];
    const float* ad2 = (const float*)d_in[9];
    const float* gw  = (const float*)d_in[10];
    const float* gb  = (const float*)d_in[11];
    float* out = (float*)d_out;

    const int N = in_sizes[0] / 768;   // 50000
    const int E = in_sizes[1] / 2;     // 800000
    const int* srcA = ei;
    const int* dstA = ei + E;

    // workspace carve-up
    char* w = (char*)d_ws;
    auto alloc = [&](size_t bytes) -> void* {
        void* p = (void*)w;
        w += (bytes + 255) & ~(size_t)255;
        return p;
    };
    float* bufH   = (float*)alloc((size_t)N * 256 * 4);  // h (layer features)
    float* bufX   = (float*)alloc((size_t)N * 256 * 4);  // aggregated/relu output
    float* asrc   = (float*)alloc((size_t)N * 4);
    float* adst   = (float*)alloc((size_t)N * 4);
    float* gate   = (float*)alloc((size_t)N * 4);
    int*   counts = (int*)alloc((size_t)N * 4);
    int*   rowptr = (int*)alloc((size_t)(N + 1) * 4);
    int*   cursor = (int*)alloc((size_t)N * 4);
    int*   colbuf = (int*)alloc((size_t)E * 4);
    float* scal   = (float*)alloc(8 * 4);
    float* gout   = (float*)alloc(256 * 4);

    const int eb = (E + 255) / 256;
    const int nb4 = (N + 3) / 4;

    // CSR by dst (reused by both layers)
    hipMemsetAsync(counts, 0, (size_t)N * 4, stream);
    k_degree<<<eb, 256, 0, stream>>>(dstA, counts, E);
    k_scan<<<1, 256, 0, stream>>>(counts, rowptr, cursor, N);
    k_scatter<<<eb, 256, 0, stream>>>(srcA, dstA, cursor, colbuf, E);

    // layer 1
    k_gemm<<<dim3(4, (N + 63) / 64), 256, 0, stream>>>(x, W1, bufH, N, 768, 256);
    k_att<<<nb4, 256, 0, stream>>>(bufH, as1, ad1, asrc, adst, N);
    k_agg<<<nb4, 256, 0, stream>>>(bufH, asrc, adst, rowptr, colbuf, b1, bufX, N);

    // layer 2
    k_gemm<<<dim3(4, (N + 63) / 64), 256, 0, stream>>>(bufX, W2, bufH, N, 256, 256);
    k_att<<<nb4, 256, 0, stream>>>(bufH, as2, ad2, asrc, adst, N);
    k_agg<<<nb4, 256, 0, stream>>>(bufH, asrc, adst, rowptr, colbuf, b2, bufX, N);

    // global attention
    k_gate<<<nb4, 256, 0, stream>>>(bufX, gw, gb, gate, N);
    k_gred<<<1, 256, 0, stream>>>(gate, N, scal, gout);
    k_gout<<<256, 256, 0, stream>>>(bufX, gate, scal, gout, N);
    k_final<<<1, 256, 0, stream>>>(gout, scal, out);
}

// Round 2
// 881.395 us; speedup vs baseline: 1.4046x; 1.4046x over previous
//
#include <hip/hip_runtime.h>

#define WAVE 64
#define LRELU(x) ((x) > 0.0f ? (x) : 0.2f * (x))

typedef __attribute__((ext_vector_type(8))) short bf16x8;
typedef __attribute__((ext_vector_type(4))) float f32x4;

__device__ inline unsigned short f2bf_hi(float f) {
    unsigned u = __builtin_bit_cast(unsigned, f);
    u += 0x7FFF + ((u >> 16) & 1);
    return (unsigned short)(u >> 16);
}
__device__ inline float bf2f(unsigned short h) {
    unsigned u = ((unsigned)h) << 16;
    return __builtin_bit_cast(float, u);
}

// ---------------- split-bf16 MFMA GEMM: C[M,256] = A[M,K] @ B[K,256]
// BThi/BTlo: [256][K] bf16, transposed + hi/lo split (precomputed).
// A split into hi/lo during LDS staging. 3-term: hi*hi + hi*lo + lo*hi.
// Block: 64 rows x 256 cols, 4 waves each own 64 cols. BK=32.
// LDS fragment-major: frag (tile,q) = 256B contiguous, lane-indexed *16B -> conflict-free b128 reads.
__global__ __launch_bounds__(256) void k_gemm_mfma(const float* __restrict__ A,
                                                   const unsigned short* __restrict__ BThi,
                                                   const unsigned short* __restrict__ BTlo,
                                                   float* __restrict__ C, int M, int K) {
    __shared__ char smem[40960];
    unsigned short* AHI = (unsigned short*)smem;             // [mt0..3][q0..3]*128 shorts
    unsigned short* ALO = (unsigned short*)(smem + 4096);
    unsigned short* BHI = (unsigned short*)(smem + 8192);    // [ntile0..15][q0..3]*128 shorts
    unsigned short* BLO = (unsigned short*)(smem + 24576);

    const int tid = threadIdx.x;
    const int lane = tid & 63;
    const int w = tid >> 6;
    const int m16 = lane & 15;
    const int q = lane >> 4;
    const int row0 = blockIdx.x * 64;

    f32x4 acc[4][4];
#pragma unroll
    for (int i = 0; i < 4; i++)
#pragma unroll
        for (int j = 0; j < 4; j++) acc[i][j] = (f32x4){0.f, 0.f, 0.f, 0.f};

    // A staging assignment: float4 indices 2*tid, 2*tid+1 of the 64x32 tile (512 float4s)
    const int i0 = tid * 2;
    const int arow = i0 >> 3;        // 0..63 (both float4s land in same row)
    const int acol4 = i0 & 7;        // 0,2,4,6

    for (int k0 = 0; k0 < K; k0 += 32) {
        // ---- stage A (fp32 -> hi/lo bf16, fragment-major)
        {
            int grow = row0 + arow;
            float4 v0, v1;
            if (grow < M) {
                const float4* pa = (const float4*)&A[(size_t)grow * K + k0];
                v0 = pa[acol4];
                v1 = pa[acol4 + 1];
            } else {
                v0 = make_float4(0.f, 0.f, 0.f, 0.f);
                v1 = v0;
            }
            float fs[8] = {v0.x, v0.y, v0.z, v0.w, v1.x, v1.y, v1.z, v1.w};
            int mt = arow >> 4, mm = arow & 15;
#pragma unroll
            for (int h = 0; h < 2; h++) {
                int k = (acol4 + h) * 4;
                int qq = k >> 3, j0 = k & 7;
                unsigned long long phi = 0, plo = 0;
#pragma unroll
                for (int e = 0; e < 4; e++) {
                    float f = fs[h * 4 + e];
                    unsigned short hb = f2bf_hi(f);
                    unsigned short lb = f2bf_hi(f - bf2f(hb));
                    phi |= ((unsigned long long)hb) << (16 * e);
                    plo |= ((unsigned long long)lb) << (16 * e);
                }
                int off = (mt * 4 + qq) * 128 + mm * 8 + j0;  // shorts
                *(unsigned long long*)&AHI[off] = phi;
                *(unsigned long long*)&ALO[off] = plo;
            }
        }
        // ---- stage B (bf16 copy, fragment-major; thread t owns row n=t)
        {
            int n = tid;
            const float4* pbh = (const float4*)&BThi[(size_t)n * K + k0];
            const float4* pbl = (const float4*)&BTlo[(size_t)n * K + k0];
            int ntile = n >> 4, nn = n & 15;
#pragma unroll
            for (int qq = 0; qq < 4; qq++) {
                *(float4*)&BHI[(ntile * 4 + qq) * 128 + nn * 8] = pbh[qq];
                *(float4*)&BLO[(ntile * 4 + qq) * 128 + nn * 8] = pbl[qq];
            }
        }
        __syncthreads();

        bf16x8 ah[4], al[4], bh[4], bl[4];
#pragma unroll
        for (int mt = 0; mt < 4; mt++) {
            ah[mt] = *(bf16x8*)&AHI[(mt * 4 + q) * 128 + m16 * 8];
            al[mt] = *(bf16x8*)&ALO[(mt * 4 + q) * 128 + m16 * 8];
        }
#pragma unroll
        for (int nt = 0; nt < 4; nt++) {
            int ntile = w * 4 + nt;
            bh[nt] = *(bf16x8*)&BHI[(ntile * 4 + q) * 128 + m16 * 8];
            bl[nt] = *(bf16x8*)&BLO[(ntile * 4 + q) * 128 + m16 * 8];
        }
#pragma unroll
        for (int mt = 0; mt < 4; mt++)
#pragma unroll
            for (int nt = 0; nt < 4; nt++) {
                acc[mt][nt] = __builtin_amdgcn_mfma_f32_16x16x32_bf16(ah[mt], bh[nt], acc[mt][nt], 0, 0, 0);
                acc[mt][nt] = __builtin_amdgcn_mfma_f32_16x16x32_bf16(ah[mt], bl[nt], acc[mt][nt], 0, 0, 0);
                acc[mt][nt] = __builtin_amdgcn_mfma_f32_16x16x32_bf16(al[mt], bh[nt], acc[mt][nt], 0, 0, 0);
            }
        __syncthreads();
    }

    // epilogue: C/D layout col = lane&15, row = q*4 + reg
#pragma unroll
    for (int mt = 0; mt < 4; mt++)
#pragma unroll
        for (int r = 0; r < 4; r++) {
            int row = row0 + mt * 16 + q * 4 + r;
            if (row < M) {
#pragma unroll
                for (int nt = 0; nt < 4; nt++)
                    C[(size_t)row * 256 + w * 64 + nt * 16 + m16] = acc[mt][nt][r];
            }
        }
}

// ---------------- W [K][256] fp32 -> BThi/BTlo [256][K] bf16 (transpose + split)
__global__ __launch_bounds__(256) void k_convB(const float* __restrict__ W,
                                               unsigned short* __restrict__ BThi,
                                               unsigned short* __restrict__ BTlo, int K) {
    int idx = blockIdx.x * 256 + threadIdx.x;  // K*256 total
    int k = idx >> 8, n = idx & 255;
    if (k >= K) return;
    float f = W[(size_t)k * 256 + n];
    unsigned short hb = f2bf_hi(f);
    unsigned short lb = f2bf_hi(f - bf2f(hb));
    BThi[(size_t)n * K + k] = hb;
    BTlo[(size_t)n * K + k] = lb;
}

// ---------------- per-node dot products: asrc[i] = h[i,:].as, adst[i] = h[i,:].ad
__global__ __launch_bounds__(256) void k_att(const float* __restrict__ h,
                                             const float* __restrict__ att_s,
                                             const float* __restrict__ att_d,
                                             float* __restrict__ asrc,
                                             float* __restrict__ adst, int N) {
    int wid = threadIdx.x >> 6;
    int lane = threadIdx.x & 63;
    int node = blockIdx.x * 4 + wid;
    if (node >= N) return;
    float4 hv = *(const float4*)&h[(size_t)node * 256 + lane * 4];
    float4 sv = *(const float4*)&att_s[lane * 4];
    float4 dv = *(const float4*)&att_d[lane * 4];
    float s = hv.x * sv.x + hv.y * sv.y + hv.z * sv.z + hv.w * sv.w;
    float d = hv.x * dv.x + hv.y * dv.y + hv.z * dv.z + hv.w * dv.w;
#pragma unroll
    for (int off = 32; off; off >>= 1) {
        s += __shfl_xor(s, off);
        d += __shfl_xor(d, off);
    }
    if (lane == 0) { asrc[node] = s; adst[node] = d; }
}

// ---------------- gate[i] = h[i,:].gw + gb
__global__ __launch_bounds__(256) void k_gate(const float* __restrict__ h,
                                              const float* __restrict__ gw,
                                              const float* __restrict__ gb,
                                              float* __restrict__ gate, int N) {
    int wid = threadIdx.x >> 6;
    int lane = threadIdx.x & 63;
    int node = blockIdx.x * 4 + wid;
    if (node >= N) return;
    float4 hv = *(const float4*)&h[(size_t)node * 256 + lane * 4];
    float4 gv = *(const float4*)&gw[lane * 4];
    float s = hv.x * gv.x + hv.y * gv.y + hv.z * gv.z + hv.w * gv.w;
#pragma unroll
    for (int off = 32; off; off >>= 1) s += __shfl_xor(s, off);
    if (lane == 0) gate[node] = s + gb[0];
}

// ---------------- CSR build
__global__ __launch_bounds__(256) void k_degree(const int* __restrict__ dst,
                                                int* __restrict__ counts, int E) {
    int e = blockIdx.x * 256 + threadIdx.x;
    if (e < E) atomicAdd(&counts[dst[e]], 1);
}

// hierarchical exclusive scan of counts -> rowptr/cursor
__global__ __launch_bounds__(256) void k_part(const int* __restrict__ counts,
                                              int* __restrict__ psum, int N) {
    __shared__ int red[256];
    int tid = threadIdx.x;
    int i = blockIdx.x * 256 + tid;
    red[tid] = (i < N) ? counts[i] : 0;
    __syncthreads();
    for (int off = 128; off; off >>= 1) {
        if (tid < off) red[tid] += red[tid + off];
        __syncthreads();
    }
    if (tid == 0) psum[blockIdx.x] = red[0];
}

__global__ __launch_bounds__(256) void k_scan_part(int* __restrict__ psum, int nb,
                                                   int* __restrict__ total_out) {
    __shared__ int s[256];
    int tid = threadIdx.x;
    int v = (tid < nb) ? psum[tid] : 0;
    s[tid] = v;
    __syncthreads();
    for (int off = 1; off < 256; off <<= 1) {
        int t = (tid >= off) ? s[tid - off] : 0;
        __syncthreads();
        s[tid] += t;
        __syncthreads();
    }
    if (tid < nb) psum[tid] = s[tid] - v;  // exclusive
    if (tid == 255) *total_out = s[255];
}

__global__ __launch_bounds__(256) void k_rowptr(const int* __restrict__ counts,
                                                const int* __restrict__ psum,
                                                int* __restrict__ rowptr,
                                                int* __restrict__ cursor, int N) {
    __shared__ int s[256];
    int tid = threadIdx.x;
    int i = blockIdx.x * 256 + tid;
    int v = (i < N) ? counts[i] : 0;
    s[tid] = v;
    __syncthreads();
    for (int off = 1; off < 256; off <<= 1) {
        int t = (tid >= off) ? s[tid - off] : 0;
        __syncthreads();
        s[tid] += t;
        __syncthreads();
    }
    if (i < N) {
        int excl = psum[blockIdx.x] + s[tid] - v;
        rowptr[i] = excl;
        cursor[i] = excl;
    }
}

__global__ __launch_bounds__(256) void k_scatter(const int* __restrict__ src,
                                                 const int* __restrict__ dst,
                                                 int* __restrict__ cursor,
                                                 int* __restrict__ col, int E) {
    int e = blockIdx.x * 256 + threadIdx.x;
    if (e < E) {
        int p = atomicAdd(&cursor[dst[e]], 1);
        col[p] = src[e];
    }
}

// ---------------- GAT aggregation (wave per node): softmax over in-edges + self loop,
// out[i,:] = relu( sum alpha_j * h[src_j,:] + bias )
__global__ __launch_bounds__(256) void k_agg(const float* __restrict__ h,
                                             const float* __restrict__ asrc,
                                             const float* __restrict__ adst,
                                             const int* __restrict__ rowptr,
                                             const int* __restrict__ col,
                                             const float* __restrict__ bias,
                                             float* __restrict__ out, int N) {
    int wid = threadIdx.x >> 6;
    int lane = threadIdx.x & 63;
    int node = blockIdx.x * 4 + wid;
    if (node >= N) return;
    int start = rowptr[node];
    int end = rowptr[node + 1];
    float ad = adst[node];
    float eself = asrc[node] + ad;
    eself = LRELU(eself);
    float m = eself;
    for (int j = start + lane; j < end; j += WAVE) {
        float e = asrc[col[j]] + ad;
        e = LRELU(e);
        m = fmaxf(m, e);
    }
#pragma unroll
    for (int off = 32; off; off >>= 1) m = fmaxf(m, __shfl_xor(m, off));
    float denom = 0.0f;
    float ax = 0.f, ay = 0.f, az = 0.f, aw = 0.f;
    {
        float wgt = __expf(eself - m);
        denom += wgt;
        float4 hv = *(const float4*)&h[(size_t)node * 256 + lane * 4];
        ax = fmaf(wgt, hv.x, ax); ay = fmaf(wgt, hv.y, ay);
        az = fmaf(wgt, hv.z, az); aw = fmaf(wgt, hv.w, aw);
    }
    for (int j = start; j < end; j++) {
        int s = col[j];
        float e = asrc[s] + ad;
        e = LRELU(e);
        float wgt = __expf(e - m);
        denom += wgt;
        float4 hv = *(const float4*)&h[(size_t)s * 256 + lane * 4];
        ax = fmaf(wgt, hv.x, ax); ay = fmaf(wgt, hv.y, ay);
        az = fmaf(wgt, hv.z, az); aw = fmaf(wgt, hv.w, aw);
    }
    float inv = 1.0f / (denom + 1e-16f);
    float4 bv = *(const float4*)&bias[lane * 4];
    float4 o;
    o.x = fmaxf(ax * inv + bv.x, 0.0f);
    o.y = fmaxf(ay * inv + bv.y, 0.0f);
    o.z = fmaxf(az * inv + bv.z, 0.0f);
    o.w = fmaxf(aw * inv + bv.w, 0.0f);
    *(float4*)&out[(size_t)node * 256 + lane * 4] = o;
}

// ---------------- global attention
__global__ __launch_bounds__(256) void k_gred(const float* __restrict__ gate, int N,
                                              float* __restrict__ scal,
                                              float* __restrict__ gout) {
    __shared__ float red[256];
    int tid = threadIdx.x;
    float m = -3.0e38f;
    for (int i = tid; i < N; i += 256) m = fmaxf(m, gate[i]);
    red[tid] = m;
    __syncthreads();
    for (int off = 128; off; off >>= 1) {
        if (tid < off) red[tid] = fmaxf(red[tid], red[tid + off]);
        __syncthreads();
    }
    float gmax = red[0];
    __syncthreads();
    float s = 0.0f;
    for (int i = tid; i < N; i += 256) s += __expf(gate[i] - gmax);
    red[tid] = s;
    __syncthreads();
    for (int off = 128; off; off >>= 1) {
        if (tid < off) red[tid] += red[tid + off];
        __syncthreads();
    }
    if (tid == 0) { scal[0] = gmax; scal[1] = red[0]; }
    gout[tid] = 0.0f;
}

__global__ __launch_bounds__(256) void k_gout(const float* __restrict__ h,
                                              const float* __restrict__ gate,
                                              const float* __restrict__ scal,
                                              float* __restrict__ gout, int N) {
    int f = threadIdx.x;
    float gmax = scal[0];
    float acc = 0.0f;
    for (int i = blockIdx.x; i < N; i += gridDim.x) {
        float w = __expf(gate[i] - gmax);
        acc = fmaf(w, h[(size_t)i * 256 + f], acc);
    }
    atomicAdd(&gout[f], acc);
}

__global__ __launch_bounds__(256) void k_final(const float* __restrict__ gout,
                                               const float* __restrict__ scal,
                                               float* __restrict__ out) {
    int f = threadIdx.x;
    out[f] = gout[f] / scal[1];
}

extern "C" void kernel_launch(void* const* d_in, const int* in_sizes, int n_in,
                              void* d_out, int out_size, void* d_ws, size_t ws_size,
                              hipStream_t stream) {
    const float* x   = (const float*)d_in[0];
    const int*   ei  = (const int*)d_in[1];
    const float* W1  = (const float*)d_in[2];
    const float* b1  = (const float*)d_in[3];
    const float* as1 = (const float*)d_in[4];
    const float* ad1 = (const float*)d_in[5];
    const float* W2  = (const float*)d_in[6];
    const float* b2  = (const float*)d_in[7];
    const float* as2 = (const float*)d_in[8];
    const float* ad2 = (const float*)d_in[9];
    const float* gw  = (const float*)d_in[10];
    const float* gb  = (const float*)d_in[11];
    float* out = (float*)d_out;

    const int N = in_sizes[0] / 768;   // 50000
    const int E = in_sizes[1] / 2;     // 800000
    const int* srcA = ei;
    const int* dstA = ei + E;

    char* w = (char*)d_ws;
    auto alloc = [&](size_t bytes) -> void* {
        void* p = (void*)w;
        w += (bytes + 255) & ~(size_t)255;
        return p;
    };
    float* bufH   = (float*)alloc((size_t)N * 256 * 4);
    float* bufX   = (float*)alloc((size_t)N * 256 * 4);
    float* asrc   = (float*)alloc((size_t)N * 4);
    float* adst   = (float*)alloc((size_t)N * 4);
    float* gate   = (float*)alloc((size_t)N * 4);
    int*   counts = (int*)alloc((size_t)N * 4);
    int*   rowptr = (int*)alloc((size_t)(N + 1) * 4);
    int*   cursor = (int*)alloc((size_t)N * 4);
    int*   colbuf = (int*)alloc((size_t)E * 4);
    int*   psum   = (int*)alloc(256 * 4);
    float* scal   = (float*)alloc(8 * 4);
    float* gout   = (float*)alloc(256 * 4);
    unsigned short* BT1h = (unsigned short*)alloc((size_t)256 * 768 * 2);
    unsigned short* BT1l = (unsigned short*)alloc((size_t)256 * 768 * 2);
    unsigned short* BT2h = (unsigned short*)alloc((size_t)256 * 256 * 2);
    unsigned short* BT2l = (unsigned short*)alloc((size_t)256 * 256 * 2);

    const int eb  = (E + 255) / 256;
    const int nb4 = (N + 3) / 4;
    const int nb  = (N + 255) / 256;
    const int gb_rows = (N + 63) / 64;

    // weight split/transpose
    k_convB<<<768, 256, 0, stream>>>(W1, BT1h, BT1l, 768);
    k_convB<<<256, 256, 0, stream>>>(W2, BT2h, BT2l, 256);

    // CSR by dst
    hipMemsetAsync(counts, 0, (size_t)N * 4, stream);
    k_degree<<<eb, 256, 0, stream>>>(dstA, counts, E);
    k_part<<<nb, 256, 0, stream>>>(counts, psum, N);
    k_scan_part<<<1, 256, 0, stream>>>(psum, nb, rowptr + N);
    k_rowptr<<<nb, 256, 0, stream>>>(counts, psum, rowptr, cursor, N);
    k_scatter<<<eb, 256, 0, stream>>>(srcA, dstA, cursor, colbuf, E);

    // layer 1
    k_gemm_mfma<<<gb_rows, 256, 0, stream>>>(x, BT1h, BT1l, bufH, N, 768);
    k_att<<<nb4, 256, 0, stream>>>(bufH, as1, ad1, asrc, adst, N);
    k_agg<<<nb4, 256, 0, stream>>>(bufH, asrc, adst, rowptr, colbuf, b1, bufX, N);

    // layer 2
    k_gemm_mfma<<<gb_rows, 256, 0, stream>>>(bufX, BT2h, BT2l, bufH, N, 256);
    k_att<<<nb4, 256, 0, stream>>>(bufH, as2, ad2, asrc, adst, N);
    k_agg<<<nb4, 256, 0, stream>>>(bufH, asrc, adst, rowptr, colbuf, b2, bufX, N);

    // global attention
    k_gate<<<nb4, 256, 0, stream>>>(bufX, gw, gb, gate, N);
    k_gred<<<1, 256, 0, stream>>>(gate, N, scal, gout);
    k_gout<<<256, 256, 0, stream>>>(bufX, gate, scal, gout, N);
    k_final<<<1, 256, 0, stream>>>(gout, scal, out);
}

// Round 4
// 786.295 us; speedup vs baseline: 1.5744x; 1.1209x over previous
//
#include <hip/hip_runtime.h>

#define WAVE 64
#define LRELU(x) ((x) > 0.0f ? (x) : 0.2f * (x))

typedef __attribute__((ext_vector_type(8))) short bf16x8;
typedef __attribute__((ext_vector_type(4))) float f32x4;

__device__ __forceinline__ void gld16(const void* g, void* l) {
    __builtin_amdgcn_global_load_lds((const __attribute__((address_space(1))) unsigned int*)g,
                                     (__attribute__((address_space(3))) unsigned int*)l,
                                     16, 0, 0);
}

__device__ __forceinline__ unsigned short f2bf_hi(float f) {
    unsigned u = __builtin_bit_cast(unsigned, f);
    u += 0x7FFF + ((u >> 16) & 1);
    return (unsigned short)(u >> 16);
}

// split 8 fp32 -> bf16 hi/lo fragments (3-term Ootomo split, validated round 2)
__device__ __forceinline__ void split8(f32x4 a, f32x4 b, bf16x8& hi, bf16x8& lo) {
    float f[8] = {a[0], a[1], a[2], a[3], b[0], b[1], b[2], b[3]};
#pragma unroll
    for (int e = 0; e < 8; e++) {
        unsigned u = __builtin_bit_cast(unsigned, f[e]);
        unsigned t = u + 0x7FFF + ((u >> 16) & 1);
        float hf = __builtin_bit_cast(float, t & 0xFFFF0000u);
        float fl = f[e] - hf;
        unsigned u2 = __builtin_bit_cast(unsigned, fl);
        unsigned t2 = u2 + 0x7FFF + ((u2 >> 16) & 1);
        hi[e] = (short)(t >> 16);
        lo[e] = (short)(t2 >> 16);
    }
}

// ============ GEMM layer1: C[M,256] = A_f32[M,K] @ B; B given as BT hi/lo [256][K] bf16.
// 128x128 tile, 4 waves; A staged fp32 via global_load_lds with 16B-block XOR swizzle,
// converted to hi/lo AFTER the LDS fragment read. 48 MFMA / K-step.
__global__ __launch_bounds__(256) void k_gemm_f32A(const float* __restrict__ A,
                                                   const unsigned short* __restrict__ Bh,
                                                   const unsigned short* __restrict__ Bl,
                                                   float* __restrict__ C, int M, int K) {
    __shared__ char smem[32768];
    char* SA  = smem;           // 128 rows x 128B fp32, 16B blocks XOR-swizzled by row&3
    char* SBH = smem + 16384;   // 128 rows x 64B bf16
    char* SBL = smem + 24576;

    const int tid = threadIdx.x, lane = tid & 63, w = tid >> 6;
    const int m16 = lane & 15, q = lane >> 4;
    const int row0 = blockIdx.x * 128, col0 = blockIdx.y * 128;

    f32x4 acc[4][4];
#pragma unroll
    for (int i = 0; i < 4; i++)
#pragma unroll
        for (int j = 0; j < 4; j++) acc[i][j] = (f32x4){0.f, 0.f, 0.f, 0.f};

    // A staging: 16 chunks of 1KB (8 rows x 128B each); wave w -> chunks 4w..4w+3
    const int a_rloc = lane >> 3;                      // row within chunk 0..7
    const int a_blk  = (lane & 7) ^ (a_rloc & 3);      // swizzled source 16B block
    // B staging: 8 chunks of 1KB (16 rows x 64B); wave w -> chunks 2w,2w+1
    const int b_rloc = lane >> 2;                      // 0..15
    const int b_kb   = (lane & 3) * 16;

    for (int k0 = 0; k0 < K; k0 += 32) {
#pragma unroll
        for (int s = 0; s < 4; s++) {
            int c = w * 4 + s;
            int grow = row0 + c * 8 + a_rloc;
            if (grow > M - 1) grow = M - 1;  // clamp: garbage rows discarded in epilogue
            gld16((const char*)A + ((size_t)grow * K + k0) * 4 + a_blk * 16,
                  SA + c * 1024);
        }
#pragma unroll
        for (int s = 0; s < 2; s++) {
            int c = w * 2 + s;
            int brow = col0 + c * 16 + b_rloc;
            gld16((const char*)Bh + ((size_t)brow * K + k0) * 2 + b_kb, SBH + c * 1024);
            gld16((const char*)Bl + ((size_t)brow * K + k0) * 2 + b_kb, SBL + c * 1024);
        }
        __syncthreads();

        bf16x8 bh[4], bl[4];
#pragma unroll
        for (int nt = 0; nt < 4; nt++) {
            int r = (w & 1) * 64 + nt * 16 + m16;
            bh[nt] = *(bf16x8*)(SBH + r * 64 + q * 16);
            bl[nt] = *(bf16x8*)(SBL + r * 64 + q * 16);
        }
#pragma unroll
        for (int mt = 0; mt < 4; mt++) {
            int r = (w >> 1) * 64 + mt * 16 + m16;
            int r3 = r & 3;
            f32x4 fa = *(f32x4*)(SA + r * 128 + ((2 * q) ^ r3) * 16);
            f32x4 fb = *(f32x4*)(SA + r * 128 + ((2 * q + 1) ^ r3) * 16);
            bf16x8 ah, al;
            split8(fa, fb, ah, al);
#pragma unroll
            for (int nt = 0; nt < 4; nt++) {
                acc[mt][nt] = __builtin_amdgcn_mfma_f32_16x16x32_bf16(ah, bh[nt], acc[mt][nt], 0, 0, 0);
                acc[mt][nt] = __builtin_amdgcn_mfma_f32_16x16x32_bf16(ah, bl[nt], acc[mt][nt], 0, 0, 0);
                acc[mt][nt] = __builtin_amdgcn_mfma_f32_16x16x32_bf16(al, bh[nt], acc[mt][nt], 0, 0, 0);
            }
        }
        __syncthreads();
    }

    const int rbase = row0 + (w >> 1) * 64;
    const int cbase = col0 + (w & 1) * 64;
#pragma unroll
    for (int mt = 0; mt < 4; mt++)
#pragma unroll
        for (int r = 0; r < 4; r++) {
            int row = rbase + mt * 16 + q * 4 + r;
            if (row < M) {
#pragma unroll
                for (int nt = 0; nt < 4; nt++)
                    C[(size_t)row * 256 + cbase + nt * 16 + m16] = acc[mt][nt][r];
            }
        }
}

// ============ GEMM layer2: A pre-split bf16 planes [Mpad][K]; same tile structure.
__global__ __launch_bounds__(256) void k_gemm_bf16A(const unsigned short* __restrict__ Ah,
                                                    const unsigned short* __restrict__ Al,
                                                    const unsigned short* __restrict__ Bh,
                                                    const unsigned short* __restrict__ Bl,
                                                    float* __restrict__ C, int M, int K) {
    __shared__ char smem[32768];
    char* SAH = smem;
    char* SAL = smem + 8192;
    char* SBH = smem + 16384;
    char* SBL = smem + 24576;

    const int tid = threadIdx.x, lane = tid & 63, w = tid >> 6;
    const int m16 = lane & 15, q = lane >> 4;
    const int row0 = blockIdx.x * 128, col0 = blockIdx.y * 128;

    f32x4 acc[4][4];
#pragma unroll
    for (int i = 0; i < 4; i++)
#pragma unroll
        for (int j = 0; j < 4; j++) acc[i][j] = (f32x4){0.f, 0.f, 0.f, 0.f};

    const int rloc = lane >> 2;          // 0..15
    const int kb   = (lane & 3) * 16;

    for (int k0 = 0; k0 < K; k0 += 32) {
#pragma unroll
        for (int s = 0; s < 2; s++) {
            int c = w * 2 + s;
            int arow = row0 + c * 16 + rloc;   // A planes padded to Mpad: no clamp needed
            int brow = col0 + c * 16 + rloc;
            gld16((const char*)Ah + ((size_t)arow * K + k0) * 2 + kb, SAH + c * 1024);
            gld16((const char*)Al + ((size_t)arow * K + k0) * 2 + kb, SAL + c * 1024);
            gld16((const char*)Bh + ((size_t)brow * K + k0) * 2 + kb, SBH + c * 1024);
            gld16((const char*)Bl + ((size_t)brow * K + k0) * 2 + kb, SBL + c * 1024);
        }
        __syncthreads();

        bf16x8 bh[4], bl[4];
#pragma unroll
        for (int nt = 0; nt < 4; nt++) {
            int r = (w & 1) * 64 + nt * 16 + m16;
            bh[nt] = *(bf16x8*)(SBH + r * 64 + q * 16);
            bl[nt] = *(bf16x8*)(SBL + r * 64 + q * 16);
        }
#pragma unroll
        for (int mt = 0; mt < 4; mt++) {
            int r = (w >> 1) * 64 + mt * 16 + m16;
            bf16x8 ah = *(bf16x8*)(SAH + r * 64 + q * 16);
            bf16x8 al = *(bf16x8*)(SAL + r * 64 + q * 16);
#pragma unroll
            for (int nt = 0; nt < 4; nt++) {
                acc[mt][nt] = __builtin_amdgcn_mfma_f32_16x16x32_bf16(ah, bh[nt], acc[mt][nt], 0, 0, 0);
                acc[mt][nt] = __builtin_amdgcn_mfma_f32_16x16x32_bf16(ah, bl[nt], acc[mt][nt], 0, 0, 0);
                acc[mt][nt] = __builtin_amdgcn_mfma_f32_16x16x32_bf16(al, bh[nt], acc[mt][nt], 0, 0, 0);
            }
        }
        __syncthreads();
    }

    const int rbase = row0 + (w >> 1) * 64;
    const int cbase = col0 + (w & 1) * 64;
#pragma unroll
    for (int mt = 0; mt < 4; mt++)
#pragma unroll
        for (int r = 0; r < 4; r++) {
            int row = rbase + mt * 16 + q * 4 + r;
            if (row < M) {
#pragma unroll
                for (int nt = 0; nt < 4; nt++)
                    C[(size_t)row * 256 + cbase + nt * 16 + m16] = acc[mt][nt][r];
            }
        }
}

// ---------------- W [K][256] fp32 -> BThi/BTlo [256][K] bf16 (transpose + split)
__global__ __launch_bounds__(256) void k_convB(const float* __restrict__ W,
                                               unsigned short* __restrict__ BThi,
                                               unsigned short* __restrict__ BTlo, int K) {
    int idx = blockIdx.x * 256 + threadIdx.x;
    int k = idx >> 8, n = idx & 255;
    if (k >= K) return;
    float f = W[(size_t)k * 256 + n];
    unsigned u = __builtin_bit_cast(unsigned, f);
    unsigned t = u + 0x7FFF + ((u >> 16) & 1);
    float hf = __builtin_bit_cast(float, t & 0xFFFF0000u);
    unsigned short lb = f2bf_hi(f - hf);
    BThi[(size_t)n * K + k] = (unsigned short)(t >> 16);
    BTlo[(size_t)n * K + k] = lb;
}

// ---------------- per-node dots: asrc[i] = h[i,:].as, adst[i] = h[i,:].ad
__global__ __launch_bounds__(256) void k_att(const float* __restrict__ h,
                                             const float* __restrict__ att_s,
                                             const float* __restrict__ att_d,
                                             float* __restrict__ asrc,
                                             float* __restrict__ adst, int N) {
    int wid = threadIdx.x >> 6;
    int lane = threadIdx.x & 63;
    int node = blockIdx.x * 4 + wid;
    if (node >= N) return;
    float4 hv = *(const float4*)&h[(size_t)node * 256 + lane * 4];
    float4 sv = *(const float4*)&att_s[lane * 4];
    float4 dv = *(const float4*)&att_d[lane * 4];
    float s = hv.x * sv.x + hv.y * sv.y + hv.z * sv.z + hv.w * sv.w;
    float d = hv.x * dv.x + hv.y * dv.y + hv.z * dv.z + hv.w * dv.w;
#pragma unroll
    for (int off = 32; off; off >>= 1) {
        s += __shfl_xor(s, off);
        d += __shfl_xor(d, off);
    }
    if (lane == 0) { asrc[node] = s; adst[node] = d; }
}

// ---------------- CSR build
__global__ __launch_bounds__(256) void k_degree(const int* __restrict__ dst,
                                                int* __restrict__ counts, int E) {
    int e = blockIdx.x * 256 + threadIdx.x;
    if (e < E) atomicAdd(&counts[dst[e]], 1);
}

__global__ __launch_bounds__(256) void k_part(const int* __restrict__ counts,
                                              int* __restrict__ psum, int N) {
    __shared__ int red[256];
    int tid = threadIdx.x;
    int i = blockIdx.x * 256 + tid;
    red[tid] = (i < N) ? counts[i] : 0;
    __syncthreads();
    for (int off = 128; off; off >>= 1) {
        if (tid < off) red[tid] += red[tid + off];
        __syncthreads();
    }
    if (tid == 0) psum[blockIdx.x] = red[0];
}

__global__ __launch_bounds__(256) void k_scan_part(int* __restrict__ psum, int nb,
                                                   int* __restrict__ total_out) {
    __shared__ int s[256];
    int tid = threadIdx.x;
    int v = (tid < nb) ? psum[tid] : 0;
    s[tid] = v;
    __syncthreads();
    for (int off = 1; off < 256; off <<= 1) {
        int t = (tid >= off) ? s[tid - off] : 0;
        __syncthreads();
        s[tid] += t;
        __syncthreads();
    }
    if (tid < nb) psum[tid] = s[tid] - v;
    if (tid == 255) *total_out = s[255];
}

__global__ __launch_bounds__(256) void k_rowptr(const int* __restrict__ counts,
                                                const int* __restrict__ psum,
                                                int* __restrict__ rowptr,
                                                int* __restrict__ cursor, int N) {
    __shared__ int s[256];
    int tid = threadIdx.x;
    int i = blockIdx.x * 256 + tid;
    int v = (i < N) ? counts[i] : 0;
    s[tid] = v;
    __syncthreads();
    for (int off = 1; off < 256; off <<= 1) {
        int t = (tid >= off) ? s[tid - off] : 0;
        __syncthreads();
        s[tid] += t;
        __syncthreads();
    }
    if (i < N) {
        int excl = psum[blockIdx.x] + s[tid] - v;
        rowptr[i] = excl;
        cursor[i] = excl;
    }
}

__global__ __launch_bounds__(256) void k_scatter(const int* __restrict__ src,
                                                 const int* __restrict__ dst,
                                                 int* __restrict__ cursor,
                                                 int* __restrict__ col, int E) {
    int e = blockIdx.x * 256 + threadIdx.x;
    if (e < E) {
        int p = atomicAdd(&cursor[dst[e]], 1);
        col[p] = src[e];
    }
}

// ---------------- phase 1: per-edge softmax weights (wave per node, lane-parallel)
__global__ __launch_bounds__(256) void k_alpha(const float* __restrict__ asrc,
                                               const float* __restrict__ adst,
                                               const int* __restrict__ rowptr,
                                               const int* __restrict__ col,
                                               float* __restrict__ walpha,
                                               float* __restrict__ wselfv,
                                               float* __restrict__ winvv, int N) {
    int wid = threadIdx.x >> 6;
    int lane = threadIdx.x & 63;
    int node = blockIdx.x * 4 + wid;
    if (node >= N) return;
    int start = rowptr[node], end = rowptr[node + 1];
    float ad = adst[node];
    float eself = asrc[node] + ad;
    eself = LRELU(eself);
    float m = eself;
    for (int j = start + lane; j < end; j += WAVE) {
        float e = asrc[col[j]] + ad;
        e = LRELU(e);
        m = fmaxf(m, e);
    }
#pragma unroll
    for (int off = 32; off; off >>= 1) m = fmaxf(m, __shfl_xor(m, off));
    float sum = 0.f;
    for (int j = start + lane; j < end; j += WAVE) {
        float e = asrc[col[j]] + ad;
        e = LRELU(e);
        float wgt = __expf(e - m);
        walpha[j] = wgt;
        sum += wgt;
    }
#pragma unroll
    for (int off = 32; off; off >>= 1) sum += __shfl_xor(sum, off);
    if (lane == 0) {
        float ws = __expf(eself - m);
        wselfv[node] = ws;
        winvv[node] = 1.0f / (sum + ws + 1e-16f);
    }
}

// ---------------- phase 2: weighted gather (wave per node), unroll x4 for MLP.
// Optionally writes fp32 out, bf16 hi/lo split planes (for next GEMM), and gate dot.
__global__ __launch_bounds__(256) void k_gather(const float* __restrict__ h,
                                                const float* __restrict__ walpha,
                                                const float* __restrict__ wselfv,
                                                const float* __restrict__ winvv,
                                                const int* __restrict__ rowptr,
                                                const int* __restrict__ col,
                                                const float* __restrict__ bias,
                                                float* __restrict__ outf,
                                                unsigned short* __restrict__ outh,
                                                unsigned short* __restrict__ outl,
                                                const float* __restrict__ gw,
                                                const float* __restrict__ gb,
                                                float* __restrict__ gatep, int N) {
    int wid = threadIdx.x >> 6;
    int lane = threadIdx.x & 63;
    int node = blockIdx.x * 4 + wid;
    if (node >= N) return;
    int j = rowptr[node], end = rowptr[node + 1];
    float ws = wselfv[node];
    float4 hv = *(const float4*)&h[(size_t)node * 256 + lane * 4];
    float ax = ws * hv.x, ay = ws * hv.y, az = ws * hv.z, aw = ws * hv.w;
    for (; j + 4 <= end; j += 4) {
        int s0 = col[j], s1 = col[j + 1], s2 = col[j + 2], s3 = col[j + 3];
        float w0 = walpha[j], w1 = walpha[j + 1], w2 = walpha[j + 2], w3 = walpha[j + 3];
        float4 h0 = *(const float4*)&h[(size_t)s0 * 256 + lane * 4];
        float4 h1 = *(const float4*)&h[(size_t)s1 * 256 + lane * 4];
        float4 h2 = *(const float4*)&h[(size_t)s2 * 256 + lane * 4];
        float4 h3 = *(const float4*)&h[(size_t)s3 * 256 + lane * 4];
        ax = fmaf(w0, h0.x, fmaf(w1, h1.x, fmaf(w2, h2.x, fmaf(w3, h3.x, ax))));
        ay = fmaf(w0, h0.y, fmaf(w1, h1.y, fmaf(w2, h2.y, fmaf(w3, h3.y, ay))));
        az = fmaf(w0, h0.z, fmaf(w1, h1.z, fmaf(w2, h2.z, fmaf(w3, h3.z, az))));
        aw = fmaf(w0, h0.w, fmaf(w1, h1.w, fmaf(w2, h2.w, fmaf(w3, h3.w, aw))));
    }
    for (; j < end; j++) {
        int s = col[j];
        float wgt = walpha[j];
        float4 hx = *(const float4*)&h[(size_t)s * 256 + lane * 4];
        ax = fmaf(wgt, hx.x, ax); ay = fmaf(wgt, hx.y, ay);
        az = fmaf(wgt, hx.z, az); aw = fmaf(wgt, hx.w, aw);
    }
    float inv = winvv[node];
    float4 bv = *(const float4*)&bias[lane * 4];
    float ox = fmaxf(fmaf(ax, inv, bv.x), 0.0f);
    float oy = fmaxf(fmaf(ay, inv, bv.y), 0.0f);
    float oz = fmaxf(fmaf(az, inv, bv.z), 0.0f);
    float ow = fmaxf(fmaf(aw, inv, bv.w), 0.0f);
    if (outf) {
        float4 o = make_float4(ox, oy, oz, ow);
        *(float4*)&outf[(size_t)node * 256 + lane * 4] = o;
    }
    if (outh) {
        float of[4] = {ox, oy, oz, ow};
        unsigned long long ph = 0, pl = 0;
#pragma unroll
        for (int e = 0; e < 4; e++) {
            unsigned u = __builtin_bit_cast(unsigned, of[e]);
            unsigned t = u + 0x7FFF + ((u >> 16) & 1);
            float hf = __builtin_bit_cast(float, t & 0xFFFF0000u);
            float fl = of[e] - hf;
            unsigned u2 = __builtin_bit_cast(unsigned, fl);
            unsigned t2 = u2 + 0x7FFF + ((u2 >> 16) & 1);
            ph |= ((unsigned long long)(t >> 16)) << (16 * e);
            pl |= ((unsigned long long)(t2 >> 16)) << (16 * e);
        }
        *(unsigned long long*)&outh[(size_t)node * 256 + lane * 4] = ph;
        *(unsigned long long*)&outl[(size_t)node * 256 + lane * 4] = pl;
    }
    if (gatep) {
        float4 gv = *(const float4*)&gw[lane * 4];
        float s = ox * gv.x + oy * gv.y + oz * gv.z + ow * gv.w;
#pragma unroll
        for (int off = 32; off; off >>= 1) s += __shfl_xor(s, off);
        if (lane == 0) gatep[node] = s + gb[0];
    }
}

// ---------------- global attention: partial max (64 blocks)
__global__ __launch_bounds__(256) void k_pmax(const float* __restrict__ gate, int N,
                                              float* __restrict__ pmax) {
    __shared__ float red[256];
    int tid = threadIdx.x;
    float m = -3.0e38f;
    for (int i = blockIdx.x * 256 + tid; i < N; i += gridDim.x * 256) m = fmaxf(m, gate[i]);
    red[tid] = m;
    __syncthreads();
    for (int off = 128; off; off >>= 1) {
        if (tid < off) red[tid] = fmaxf(red[tid], red[tid + off]);
        __syncthreads();
    }
    if (tid == 0) pmax[blockIdx.x] = red[0];
}

// fold partial maxes, zero accumulators
__global__ __launch_bounds__(256) void k_gmid(const float* __restrict__ pmax, int nb,
                                              float* __restrict__ scal,
                                              float* __restrict__ gout) {
    __shared__ float red[256];
    int tid = threadIdx.x;
    red[tid] = (tid < nb) ? pmax[tid] : -3.0e38f;
    __syncthreads();
    for (int off = 128; off; off >>= 1) {
        if (tid < off) red[tid] = fmaxf(red[tid], red[tid + off]);
        __syncthreads();
    }
    if (tid == 0) { scal[0] = red[0]; scal[1] = 0.0f; }
    gout[tid] = 0.0f;
}

// weighted feature sum + denom accumulation (scal_rw: [0]=gmax read, [1]=denom accum)
__global__ __launch_bounds__(256) void k_gout(const float* __restrict__ h,
                                              const float* __restrict__ gate,
                                              float* __restrict__ scal_rw,
                                              float* __restrict__ gout, int N) {
    int f = threadIdx.x;
    float gmax = scal_rw[0];
    float acc = 0.0f, sumw = 0.0f;
    for (int i = blockIdx.x; i < N; i += gridDim.x) {
        float w = __expf(gate[i] - gmax);
        acc = fmaf(w, h[(size_t)i * 256 + f], acc);
        sumw += w;
    }
    atomicAdd(&gout[f], acc);
    if (f == 0) atomicAdd(&scal_rw[1], sumw);
}

__global__ __launch_bounds__(256) void k_final(const float* __restrict__ gout,
                                               const float* __restrict__ scal,
                                               float* __restrict__ out) {
    int f = threadIdx.x;
    out[f] = gout[f] / scal[1];
}

extern "C" void kernel_launch(void* const* d_in, const int* in_sizes, int n_in,
                              void* d_out, int out_size, void* d_ws, size_t ws_size,
                              hipStream_t stream) {
    const float* x   = (const float*)d_in[0];
    const int*   ei  = (const int*)d_in[1];
    const float* W1  = (const float*)d_in[2];
    const float* b1  = (const float*)d_in[3];
    const float* as1 = (const float*)d_in[4];
    const float* ad1 = (const float*)d_in[5];
    const float* W2  = (const float*)d_in[6];
    const float* b2  = (const float*)d_in[7];
    const float* as2 = (const float*)d_in[8];
    const float* ad2 = (const float*)d_in[9];
    const float* gw  = (const float*)d_in[10];
    const float* gb  = (const float*)d_in[11];
    float* out = (float*)d_out;

    const int N = in_sizes[0] / 768;   // 50000
    const int E = in_sizes[1] / 2;     // 800000
    const int Mpad = (N + 127) & ~127; // 50048
    const int* srcA = ei;
    const int* dstA = ei + E;

    char* w = (char*)d_ws;
    auto alloc = [&](size_t bytes) -> void* {
        void* p = (void*)w;
        w += (bytes + 255) & ~(size_t)255;
        return p;
    };
    float* bufH = (float*)alloc((size_t)N * 256 * 4);              // GEMM out (both layers)
    unsigned short* X2h = (unsigned short*)alloc((size_t)Mpad * 256 * 2);
    unsigned short* X2l = (unsigned short*)alloc((size_t)Mpad * 256 * 2);
    float* bufX = (float*)X2h;  // ALIAS: X2 planes dead after GEMM2; bufX written by gather2 (after)
    float* asrc   = (float*)alloc((size_t)N * 4);
    float* adst   = (float*)alloc((size_t)N * 4);
    float* gate   = (float*)alloc((size_t)N * 4);
    float* wselfv = (float*)alloc((size_t)N * 4);
    float* winvv  = (float*)alloc((size_t)N * 4);
    int*   counts = (int*)alloc((size_t)N * 4);
    int*   rowptr = (int*)alloc((size_t)(N + 1) * 4);
    int*   cursor = (int*)alloc((size_t)N * 4);
    int*   colbuf = (int*)alloc((size_t)E * 4);
    float* walpha = (float*)alloc((size_t)E * 4);
    int*   psum   = (int*)alloc(256 * 4);
    float* pmax   = (float*)alloc(256 * 4);
    float* scal   = (float*)alloc(8 * 4);
    float* gout   = (float*)alloc(256 * 4);
    unsigned short* BT1h = (unsigned short*)alloc((size_t)256 * 768 * 2);
    unsigned short* BT1l = (unsigned short*)alloc((size_t)256 * 768 * 2);
    unsigned short* BT2h = (unsigned short*)alloc((size_t)256 * 256 * 2);
    unsigned short* BT2l = (unsigned short*)alloc((size_t)256 * 256 * 2);

    const int eb  = (E + 255) / 256;
    const int nb4 = (N + 3) / 4;
    const int nb  = (N + 255) / 256;
    const dim3 gg(Mpad / 128, 2);

    // weight split/transpose
    k_convB<<<768, 256, 0, stream>>>(W1, BT1h, BT1l, 768);
    k_convB<<<256, 256, 0, stream>>>(W2, BT2h, BT2l, 256);

    // CSR by dst
    (void)hipMemsetAsync(counts, 0, (size_t)N * 4, stream);
    k_degree<<<eb, 256, 0, stream>>>(dstA, counts, E);
    k_part<<<nb, 256, 0, stream>>>(counts, psum, N);
    k_scan_part<<<1, 256, 0, stream>>>(psum, nb, rowptr + N);
    k_rowptr<<<nb, 256, 0, stream>>>(counts, psum, rowptr, cursor, N);
    k_scatter<<<eb, 256, 0, stream>>>(srcA, dstA, cursor, colbuf, E);

    // layer 1
    k_gemm_f32A<<<gg, 256, 0, stream>>>(x, BT1h, BT1l, bufH, N, 768);
    k_att<<<nb4, 256, 0, stream>>>(bufH, as1, ad1, asrc, adst, N);
    k_alpha<<<nb4, 256, 0, stream>>>(asrc, adst, rowptr, colbuf, walpha, wselfv, winvv, N);
    k_gather<<<nb4, 256, 0, stream>>>(bufH, walpha, wselfv, winvv, rowptr, colbuf, b1,
                                      nullptr, X2h, X2l, nullptr, nullptr, nullptr, N);

    // layer 2
    k_gemm_bf16A<<<gg, 256, 0, stream>>>(X2h, X2l, BT2h, BT2l, bufH, N, 256);
    k_att<<<nb4, 256, 0, stream>>>(bufH, as2, ad2, asrc, adst, N);
    k_alpha<<<nb4, 256, 0, stream>>>(asrc, adst, rowptr, colbuf, walpha, wselfv, winvv, N);
    k_gather<<<nb4, 256, 0, stream>>>(bufH, walpha, wselfv, winvv, rowptr, colbuf, b2,
                                      bufX, nullptr, nullptr, gw, gb, gate, N);

    // global attention
    k_pmax<<<64, 256, 0, stream>>>(gate, N, pmax);
    k_gmid<<<1, 256, 0, stream>>>(pmax, 64, scal, gout);
    k_gout<<<256, 256, 0, stream>>>(bufX, gate, scal, gout, N);
    k_final<<<1, 256, 0, stream>>>(gout, scal, out);
}

// Round 5
// 773.578 us; speedup vs baseline: 1.6003x; 1.0164x over previous
//
#include <hip/hip_runtime.h>

#define WAVE 64
#define LRELU(x) ((x) > 0.0f ? (x) : 0.2f * (x))

typedef __attribute__((ext_vector_type(8))) short bf16x8;
typedef __attribute__((ext_vector_type(4))) float f32x4;

__device__ __forceinline__ void gld16(const void* g, void* l) {
    __builtin_amdgcn_global_load_lds((const __attribute__((address_space(1))) unsigned int*)g,
                                     (__attribute__((address_space(3))) unsigned int*)l,
                                     16, 0, 0);
}

__device__ __forceinline__ unsigned short f2bf_hi(float f) {
    unsigned u = __builtin_bit_cast(unsigned, f);
    u += 0x7FFF + ((u >> 16) & 1);
    return (unsigned short)(u >> 16);
}

// split 8 fp32 -> bf16 hi/lo (3-term Ootomo split, validated rounds 2/4)
__device__ __forceinline__ void split8(f32x4 a, f32x4 b, bf16x8& hi, bf16x8& lo) {
    float f[8] = {a[0], a[1], a[2], a[3], b[0], b[1], b[2], b[3]};
#pragma unroll
    for (int e = 0; e < 8; e++) {
        unsigned u = __builtin_bit_cast(unsigned, f[e]);
        unsigned t = u + 0x7FFF + ((u >> 16) & 1);
        float hf = __builtin_bit_cast(float, t & 0xFFFF0000u);
        float fl = f[e] - hf;
        unsigned u2 = __builtin_bit_cast(unsigned, fl);
        unsigned t2 = u2 + 0x7FFF + ((u2 >> 16) & 1);
        hi[e] = (short)(t >> 16);
        lo[e] = (short)(t2 >> 16);
    }
}

// ============ GEMM layer1: C[M,256] = A_f32[M,K] @ B; B = BT hi/lo [256][K] bf16.
// 128x128 tile, 4 waves. A: register-prefetched fp32 (1 iter ahead), split ONCE per
// element at staging, ds_write_b128 into fragment-major bf16 LDS (conflict-free both
// sides — round-4 fp32-row layout had structural 8-way read conflicts). B via gld16.
__global__ __launch_bounds__(256) void k_gemm_f32A(const float* __restrict__ A,
                                                   const unsigned short* __restrict__ Bh,
                                                   const unsigned short* __restrict__ Bl,
                                                   float* __restrict__ C, int M, int K) {
    __shared__ char smem[32768];
    char* SAH = smem;            // A hi: 32 fragments (8 mt x 4 q) x 256B
    char* SAL = smem + 8192;     // A lo
    char* SBH = smem + 16384;    // B hi: 8 chunks x 1KB (16 rows x 64B)
    char* SBL = smem + 24576;    // B lo

    const int tid = threadIdx.x, lane = tid & 63, w = tid >> 6;
    const int m16 = lane & 15, q = lane >> 4;
    const int row0 = blockIdx.x * 128, col0 = blockIdx.y * 128;

    f32x4 acc[4][4];
#pragma unroll
    for (int i = 0; i < 4; i++)
#pragma unroll
        for (int j = 0; j < 4; j++) acc[i][j] = (f32x4){0.f, 0.f, 0.f, 0.f};

    // A staging: thread owns row tid>>1, k-half tid&1 (16 fp32 -> 2 hi + 2 lo bf16x8)
    const int s_row = tid >> 1;
    const int s_mt  = s_row >> 4, s_m16 = s_row & 15;
    const int s_q0  = (tid & 1) * 2;
    int s_grow = row0 + s_row;
    if (s_grow > M - 1) s_grow = M - 1;   // clamp: dup rows discarded in epilogue
    const f32x4* aptr = (const f32x4*)&A[(size_t)s_grow * K] + (tid & 1) * 4;
    const int s_off = (s_mt * 4 + s_q0) * 256 + s_m16 * 16;

    // B staging: 8 chunks of 1KB; wave w -> chunks 2w, 2w+1
    const int b_rloc = lane >> 2;
    const int b_kb   = (lane & 3) * 16;

    f32x4 pre0 = aptr[0], pre1 = aptr[1], pre2 = aptr[2], pre3 = aptr[3];

    for (int k0 = 0; k0 < K; k0 += 32) {
        // B via async global->LDS
#pragma unroll
        for (int s = 0; s < 2; s++) {
            int c = w * 2 + s;
            int brow = col0 + c * 16 + b_rloc;
            gld16((const char*)Bh + ((size_t)brow * K + k0) * 2 + b_kb, SBH + c * 1024);
            gld16((const char*)Bl + ((size_t)brow * K + k0) * 2 + b_kb, SBL + c * 1024);
        }
        // A: split prefetched registers, write fragment-major
        {
            bf16x8 h0, l0, h1, l1;
            split8(pre0, pre1, h0, l0);
            split8(pre2, pre3, h1, l1);
            *(bf16x8*)(SAH + s_off)       = h0;
            *(bf16x8*)(SAL + s_off)       = l0;
            *(bf16x8*)(SAH + s_off + 256) = h1;
            *(bf16x8*)(SAL + s_off + 256) = l1;
        }
        __syncthreads();

        // prefetch next iteration's A into registers (hidden under ds_read+MFMA)
        if (k0 + 32 < K) {
            aptr += 8;
            pre0 = aptr[0]; pre1 = aptr[1]; pre2 = aptr[2]; pre3 = aptr[3];
        }

        bf16x8 bh[4], bl[4];
#pragma unroll
        for (int nt = 0; nt < 4; nt++) {
            int r = (w & 1) * 64 + nt * 16 + m16;
            bh[nt] = *(bf16x8*)(SBH + r * 64 + q * 16);
            bl[nt] = *(bf16x8*)(SBL + r * 64 + q * 16);
        }
#pragma unroll
        for (int mt = 0; mt < 4; mt++) {
            int frag = ((w >> 1) * 4 + mt) * 4 + q;
            bf16x8 ah = *(bf16x8*)(SAH + frag * 256 + m16 * 16);
            bf16x8 al = *(bf16x8*)(SAL + frag * 256 + m16 * 16);
#pragma unroll
            for (int nt = 0; nt < 4; nt++) {
                acc[mt][nt] = __builtin_amdgcn_mfma_f32_16x16x32_bf16(ah, bh[nt], acc[mt][nt], 0, 0, 0);
                acc[mt][nt] = __builtin_amdgcn_mfma_f32_16x16x32_bf16(ah, bl[nt], acc[mt][nt], 0, 0, 0);
                acc[mt][nt] = __builtin_amdgcn_mfma_f32_16x16x32_bf16(al, bh[nt], acc[mt][nt], 0, 0, 0);
            }
        }
        __syncthreads();
    }

    const int rbase = row0 + (w >> 1) * 64;
    const int cbase = col0 + (w & 1) * 64;
#pragma unroll
    for (int mt = 0; mt < 4; mt++)
#pragma unroll
        for (int r = 0; r < 4; r++) {
            int row = rbase + mt * 16 + q * 4 + r;
            if (row < M) {
#pragma unroll
                for (int nt = 0; nt < 4; nt++)
                    C[(size_t)row * 256 + cbase + nt * 16 + m16] = acc[mt][nt][r];
            }
        }
}

// ============ GEMM layer2: A pre-split bf16 planes [Mpad][K]; clean gld16 path.
__global__ __launch_bounds__(256) void k_gemm_bf16A(const unsigned short* __restrict__ Ah,
                                                    const unsigned short* __restrict__ Al,
                                                    const unsigned short* __restrict__ Bh,
                                                    const unsigned short* __restrict__ Bl,
                                                    float* __restrict__ C, int M, int K) {
    __shared__ char smem[32768];
    char* SAH = smem;
    char* SAL = smem + 8192;
    char* SBH = smem + 16384;
    char* SBL = smem + 24576;

    const int tid = threadIdx.x, lane = tid & 63, w = tid >> 6;
    const int m16 = lane & 15, q = lane >> 4;
    const int row0 = blockIdx.x * 128, col0 = blockIdx.y * 128;

    f32x4 acc[4][4];
#pragma unroll
    for (int i = 0; i < 4; i++)
#pragma unroll
        for (int j = 0; j < 4; j++) acc[i][j] = (f32x4){0.f, 0.f, 0.f, 0.f};

    const int rloc = lane >> 2;
    const int kb   = (lane & 3) * 16;

    for (int k0 = 0; k0 < K; k0 += 32) {
#pragma unroll
        for (int s = 0; s < 2; s++) {
            int c = w * 2 + s;
            int arow = row0 + c * 16 + rloc;
            int brow = col0 + c * 16 + rloc;
            gld16((const char*)Ah + ((size_t)arow * K + k0) * 2 + kb, SAH + c * 1024);
            gld16((const char*)Al + ((size_t)arow * K + k0) * 2 + kb, SAL + c * 1024);
            gld16((const char*)Bh + ((size_t)brow * K + k0) * 2 + kb, SBH + c * 1024);
            gld16((const char*)Bl + ((size_t)brow * K + k0) * 2 + kb, SBL + c * 1024);
        }
        __syncthreads();

        bf16x8 bh[4], bl[4];
#pragma unroll
        for (int nt = 0; nt < 4; nt++) {
            int r = (w & 1) * 64 + nt * 16 + m16;
            bh[nt] = *(bf16x8*)(SBH + r * 64 + q * 16);
            bl[nt] = *(bf16x8*)(SBL + r * 64 + q * 16);
        }
#pragma unroll
        for (int mt = 0; mt < 4; mt++) {
            int r = (w >> 1) * 64 + mt * 16 + m16;
            bf16x8 ah = *(bf16x8*)(SAH + r * 64 + q * 16);
            bf16x8 al = *(bf16x8*)(SAL + r * 64 + q * 16);
#pragma unroll
            for (int nt = 0; nt < 4; nt++) {
                acc[mt][nt] = __builtin_amdgcn_mfma_f32_16x16x32_bf16(ah, bh[nt], acc[mt][nt], 0, 0, 0);
                acc[mt][nt] = __builtin_amdgcn_mfma_f32_16x16x32_bf16(ah, bl[nt], acc[mt][nt], 0, 0, 0);
                acc[mt][nt] = __builtin_amdgcn_mfma_f32_16x16x32_bf16(al, bh[nt], acc[mt][nt], 0, 0, 0);
            }
        }
        __syncthreads();
    }

    const int rbase = row0 + (w >> 1) * 64;
    const int cbase = col0 + (w & 1) * 64;
#pragma unroll
    for (int mt = 0; mt < 4; mt++)
#pragma unroll
        for (int r = 0; r < 4; r++) {
            int row = rbase + mt * 16 + q * 4 + r;
            if (row < M) {
#pragma unroll
                for (int nt = 0; nt < 4; nt++)
                    C[(size_t)row * 256 + cbase + nt * 16 + m16] = acc[mt][nt][r];
            }
        }
}

// ---------------- W [K][256] fp32 -> BThi/BTlo [256][K] bf16 (transpose + split)
__global__ __launch_bounds__(256) void k_convB(const float* __restrict__ W,
                                               unsigned short* __restrict__ BThi,
                                               unsigned short* __restrict__ BTlo, int K) {
    int idx = blockIdx.x * 256 + threadIdx.x;
    int k = idx >> 8, n = idx & 255;
    if (k >= K) return;
    float f = W[(size_t)k * 256 + n];
    unsigned u = __builtin_bit_cast(unsigned, f);
    unsigned t = u + 0x7FFF + ((u >> 16) & 1);
    float hf = __builtin_bit_cast(float, t & 0xFFFF0000u);
    unsigned short lb = f2bf_hi(f - hf);
    BThi[(size_t)n * K + k] = (unsigned short)(t >> 16);
    BTlo[(size_t)n * K + k] = lb;
}

// ---------------- per-node dots: asrc[i] = h[i,:].as, adst[i] = h[i,:].ad
__global__ __launch_bounds__(256) void k_att(const float* __restrict__ h,
                                             const float* __restrict__ att_s,
                                             const float* __restrict__ att_d,
                                             float* __restrict__ asrc,
                                             float* __restrict__ adst, int N) {
    int wid = threadIdx.x >> 6;
    int lane = threadIdx.x & 63;
    int node = blockIdx.x * 4 + wid;
    if (node >= N) return;
    float4 hv = *(const float4*)&h[(size_t)node * 256 + lane * 4];
    float4 sv = *(const float4*)&att_s[lane * 4];
    float4 dv = *(const float4*)&att_d[lane * 4];
    float s = hv.x * sv.x + hv.y * sv.y + hv.z * sv.z + hv.w * sv.w;
    float d = hv.x * dv.x + hv.y * dv.y + hv.z * dv.z + hv.w * dv.w;
#pragma unroll
    for (int off = 32; off; off >>= 1) {
        s += __shfl_xor(s, off);
        d += __shfl_xor(d, off);
    }
    if (lane == 0) { asrc[node] = s; adst[node] = d; }
}

// ---------------- CSR build
__global__ __launch_bounds__(256) void k_degree(const int* __restrict__ dst,
                                                int* __restrict__ counts, int E) {
    int e = blockIdx.x * 256 + threadIdx.x;
    if (e < E) atomicAdd(&counts[dst[e]], 1);
}

__global__ __launch_bounds__(256) void k_part(const int* __restrict__ counts,
                                              int* __restrict__ psum, int N) {
    __shared__ int red[256];
    int tid = threadIdx.x;
    int i = blockIdx.x * 256 + tid;
    red[tid] = (i < N) ? counts[i] : 0;
    __syncthreads();
    for (int off = 128; off; off >>= 1) {
        if (tid < off) red[tid] += red[tid + off];
        __syncthreads();
    }
    if (tid == 0) psum[blockIdx.x] = red[0];
}

__global__ __launch_bounds__(256) void k_scan_part(int* __restrict__ psum, int nb,
                                                   int* __restrict__ total_out) {
    __shared__ int s[256];
    int tid = threadIdx.x;
    int v = (tid < nb) ? psum[tid] : 0;
    s[tid] = v;
    __syncthreads();
    for (int off = 1; off < 256; off <<= 1) {
        int t = (tid >= off) ? s[tid - off] : 0;
        __syncthreads();
        s[tid] += t;
        __syncthreads();
    }
    if (tid < nb) psum[tid] = s[tid] - v;
    if (tid == 255) *total_out = s[255];
}

__global__ __launch_bounds__(256) void k_rowptr(const int* __restrict__ counts,
                                                const int* __restrict__ psum,
                                                int* __restrict__ rowptr,
                                                int* __restrict__ cursor, int N) {
    __shared__ int s[256];
    int tid = threadIdx.x;
    int i = blockIdx.x * 256 + tid;
    int v = (i < N) ? counts[i] : 0;
    s[tid] = v;
    __syncthreads();
    for (int off = 1; off < 256; off <<= 1) {
        int t = (tid >= off) ? s[tid - off] : 0;
        __syncthreads();
        s[tid] += t;
        __syncthreads();
    }
    if (i < N) {
        int excl = psum[blockIdx.x] + s[tid] - v;
        rowptr[i] = excl;
        cursor[i] = excl;
    }
}

__global__ __launch_bounds__(256) void k_scatter(const int* __restrict__ src,
                                                 const int* __restrict__ dst,
                                                 int* __restrict__ cursor,
                                                 int* __restrict__ col, int E) {
    int e = blockIdx.x * 256 + threadIdx.x;
    if (e < E) {
        int p = atomicAdd(&cursor[dst[e]], 1);
        col[p] = src[e];
    }
}

// ---------------- phase 1: per-edge softmax weights (wave per node)
__global__ __launch_bounds__(256) void k_alpha(const float* __restrict__ asrc,
                                               const float* __restrict__ adst,
                                               const int* __restrict__ rowptr,
                                               const int* __restrict__ col,
                                               float* __restrict__ walpha,
                                               float* __restrict__ wselfv,
                                               float* __restrict__ winvv, int N) {
    int wid = threadIdx.x >> 6;
    int lane = threadIdx.x & 63;
    int node = blockIdx.x * 4 + wid;
    if (node >= N) return;
    int start = rowptr[node], end = rowptr[node + 1];
    float ad = adst[node];
    float eself = asrc[node] + ad;
    eself = LRELU(eself);
    float m = eself;
    for (int j = start + lane; j < end; j += WAVE) {
        float e = asrc[col[j]] + ad;
        e = LRELU(e);
        m = fmaxf(m, e);
    }
#pragma unroll
    for (int off = 32; off; off >>= 1) m = fmaxf(m, __shfl_xor(m, off));
    float sum = 0.f;
    for (int j = start + lane; j < end; j += WAVE) {
        float e = asrc[col[j]] + ad;
        e = LRELU(e);
        float wgt = __expf(e - m);
        walpha[j] = wgt;
        sum += wgt;
    }
#pragma unroll
    for (int off = 32; off; off >>= 1) sum += __shfl_xor(sum, off);
    if (lane == 0) {
        float ws = __expf(eself - m);
        wselfv[node] = ws;
        winvv[node] = 1.0f / (sum + ws + 1e-16f);
    }
}

// ---------------- phase 2: weighted gather (wave per node), unroll x4.
__global__ __launch_bounds__(256) void k_gather(const float* __restrict__ h,
                                                const float* __restrict__ walpha,
                                                const float* __restrict__ wselfv,
                                                const float* __restrict__ winvv,
                                                const int* __restrict__ rowptr,
                                                const int* __restrict__ col,
                                                const float* __restrict__ bias,
                                                float* __restrict__ outf,
                                                unsigned short* __restrict__ outh,
                                                unsigned short* __restrict__ outl,
                                                const float* __restrict__ gw,
                                                const float* __restrict__ gb,
                                                float* __restrict__ gatep, int N) {
    int wid = threadIdx.x >> 6;
    int lane = threadIdx.x & 63;
    int node = blockIdx.x * 4 + wid;
    if (node >= N) return;
    int j = rowptr[node], end = rowptr[node + 1];
    float ws = wselfv[node];
    float4 hv = *(const float4*)&h[(size_t)node * 256 + lane * 4];
    float ax = ws * hv.x, ay = ws * hv.y, az = ws * hv.z, aw = ws * hv.w;
    for (; j + 4 <= end; j += 4) {
        int s0 = col[j], s1 = col[j + 1], s2 = col[j + 2], s3 = col[j + 3];
        float w0 = walpha[j], w1 = walpha[j + 1], w2 = walpha[j + 2], w3 = walpha[j + 3];
        float4 h0 = *(const float4*)&h[(size_t)s0 * 256 + lane * 4];
        float4 h1 = *(const float4*)&h[(size_t)s1 * 256 + lane * 4];
        float4 h2 = *(const float4*)&h[(size_t)s2 * 256 + lane * 4];
        float4 h3 = *(const float4*)&h[(size_t)s3 * 256 + lane * 4];
        ax = fmaf(w0, h0.x, fmaf(w1, h1.x, fmaf(w2, h2.x, fmaf(w3, h3.x, ax))));
        ay = fmaf(w0, h0.y, fmaf(w1, h1.y, fmaf(w2, h2.y, fmaf(w3, h3.y, ay))));
        az = fmaf(w0, h0.z, fmaf(w1, h1.z, fmaf(w2, h2.z, fmaf(w3, h3.z, az))));
        aw = fmaf(w0, h0.w, fmaf(w1, h1.w, fmaf(w2, h2.w, fmaf(w3, h3.w, aw))));
    }
    for (; j < end; j++) {
        int s = col[j];
        float wgt = walpha[j];
        float4 hx = *(const float4*)&h[(size_t)s * 256 + lane * 4];
        ax = fmaf(wgt, hx.x, ax); ay = fmaf(wgt, hx.y, ay);
        az = fmaf(wgt, hx.z, az); aw = fmaf(wgt, hx.w, aw);
    }
    float inv = winvv[node];
    float4 bv = *(const float4*)&bias[lane * 4];
    float ox = fmaxf(fmaf(ax, inv, bv.x), 0.0f);
    float oy = fmaxf(fmaf(ay, inv, bv.y), 0.0f);
    float oz = fmaxf(fmaf(az, inv, bv.z), 0.0f);
    float ow = fmaxf(fmaf(aw, inv, bv.w), 0.0f);
    if (outf) {
        float4 o = make_float4(ox, oy, oz, ow);
        *(float4*)&outf[(size_t)node * 256 + lane * 4] = o;
    }
    if (outh) {
        float of[4] = {ox, oy, oz, ow};
        unsigned long long ph = 0, pl = 0;
#pragma unroll
        for (int e = 0; e < 4; e++) {
            unsigned u = __builtin_bit_cast(unsigned, of[e]);
            unsigned t = u + 0x7FFF + ((u >> 16) & 1);
            float hf = __builtin_bit_cast(float, t & 0xFFFF0000u);
            float fl = of[e] - hf;
            unsigned u2 = __builtin_bit_cast(unsigned, fl);
            unsigned t2 = u2 + 0x7FFF + ((u2 >> 16) & 1);
            ph |= ((unsigned long long)(t >> 16)) << (16 * e);
            pl |= ((unsigned long long)(t2 >> 16)) << (16 * e);
        }
        *(unsigned long long*)&outh[(size_t)node * 256 + lane * 4] = ph;
        *(unsigned long long*)&outl[(size_t)node * 256 + lane * 4] = pl;
    }
    if (gatep) {
        float4 gv = *(const float4*)&gw[lane * 4];
        float s = ox * gv.x + oy * gv.y + oz * gv.z + ow * gv.w;
#pragma unroll
        for (int off = 32; off; off >>= 1) s += __shfl_xor(s, off);
        if (lane == 0) gatep[node] = s + gb[0];
    }
}

// ---------------- global attention
__global__ __launch_bounds__(256) void k_pmax(const float* __restrict__ gate, int N,
                                              float* __restrict__ pmax) {
    __shared__ float red[256];
    int tid = threadIdx.x;
    float m = -3.0e38f;
    for (int i = blockIdx.x * 256 + tid; i < N; i += gridDim.x * 256) m = fmaxf(m, gate[i]);
    red[tid] = m;
    __syncthreads();
    for (int off = 128; off; off >>= 1) {
        if (tid < off) red[tid] = fmaxf(red[tid], red[tid + off]);
        __syncthreads();
    }
    if (tid == 0) pmax[blockIdx.x] = red[0];
}

__global__ __launch_bounds__(256) void k_gmid(const float* __restrict__ pmax, int nb,
                                              float* __restrict__ scal,
                                              float* __restrict__ gout) {
    __shared__ float red[256];
    int tid = threadIdx.x;
    red[tid] = (tid < nb) ? pmax[tid] : -3.0e38f;
    __syncthreads();
    for (int off = 128; off; off >>= 1) {
        if (tid < off) red[tid] = fmaxf(red[tid], red[tid + off]);
        __syncthreads();
    }
    if (tid == 0) { scal[0] = red[0]; scal[1] = 0.0f; }
    gout[tid] = 0.0f;
}

__global__ __launch_bounds__(256) void k_gout(const float* __restrict__ h,
                                              const float* __restrict__ gate,
                                              float* __restrict__ scal_rw,
                                              float* __restrict__ gout, int N) {
    int f = threadIdx.x;
    float gmax = scal_rw[0];
    float acc = 0.0f, sumw = 0.0f;
    for (int i = blockIdx.x; i < N; i += gridDim.x) {
        float w = __expf(gate[i] - gmax);
        acc = fmaf(w, h[(size_t)i * 256 + f], acc);
        sumw += w;
    }
    atomicAdd(&gout[f], acc);
    if (f == 0) atomicAdd(&scal_rw[1], sumw);
}

__global__ __launch_bounds__(256) void k_final(const float* __restrict__ gout,
                                               const float* __restrict__ scal,
                                               float* __restrict__ out) {
    int f = threadIdx.x;
    out[f] = gout[f] / scal[1];
}

extern "C" void kernel_launch(void* const* d_in, const int* in_sizes, int n_in,
                              void* d_out, int out_size, void* d_ws, size_t ws_size,
                              hipStream_t stream) {
    const float* x   = (const float*)d_in[0];
    const int*   ei  = (const int*)d_in[1];
    const float* W1  = (const float*)d_in[2];
    const float* b1  = (const float*)d_in[3];
    const float* as1 = (const float*)d_in[4];
    const float* ad1 = (const float*)d_in[5];
    const float* W2  = (const float*)d_in[6];
    const float* b2  = (const float*)d_in[7];
    const float* as2 = (const float*)d_in[8];
    const float* ad2 = (const float*)d_in[9];
    const float* gw  = (const float*)d_in[10];
    const float* gb  = (const float*)d_in[11];
    float* out = (float*)d_out;

    const int N = in_sizes[0] / 768;   // 50000
    const int E = in_sizes[1] / 2;     // 800000
    const int Mpad = (N + 127) & ~127; // 50048
    const int* srcA = ei;
    const int* dstA = ei + E;

    char* w = (char*)d_ws;
    auto alloc = [&](size_t bytes) -> void* {
        void* p = (void*)w;
        w += (bytes + 255) & ~(size_t)255;
        return p;
    };
    float* bufH = (float*)alloc((size_t)N * 256 * 4);
    unsigned short* X2h = (unsigned short*)alloc((size_t)Mpad * 256 * 2);
    unsigned short* X2l = (unsigned short*)alloc((size_t)Mpad * 256 * 2);
    float* bufX = (float*)X2h;  // alias: X2 planes dead after GEMM2
    float* asrc   = (float*)alloc((size_t)N * 4);
    float* adst   = (float*)alloc((size_t)N * 4);
    float* gate   = (float*)alloc((size_t)N * 4);
    float* wselfv = (float*)alloc((size_t)N * 4);
    float* winvv  = (float*)alloc((size_t)N * 4);
    int*   counts = (int*)alloc((size_t)N * 4);
    int*   rowptr = (int*)alloc((size_t)(N + 1) * 4);
    int*   cursor = (int*)alloc((size_t)N * 4);
    int*   colbuf = (int*)alloc((size_t)E * 4);
    float* walpha = (float*)alloc((size_t)E * 4);
    int*   psum   = (int*)alloc(256 * 4);
    float* pmax   = (float*)alloc(256 * 4);
    float* scal   = (float*)alloc(8 * 4);
    float* gout   = (float*)alloc(256 * 4);
    unsigned short* BT1h = (unsigned short*)alloc((size_t)256 * 768 * 2);
    unsigned short* BT1l = (unsigned short*)alloc((size_t)256 * 768 * 2);
    unsigned short* BT2h = (unsigned short*)alloc((size_t)256 * 256 * 2);
    unsigned short* BT2l = (unsigned short*)alloc((size_t)256 * 256 * 2);

    const int eb  = (E + 255) / 256;
    const int nb4 = (N + 3) / 4;
    const int nb  = (N + 255) / 256;
    const dim3 gg(Mpad / 128, 2);

    // weight split/transpose
    k_convB<<<768, 256, 0, stream>>>(W1, BT1h, BT1l, 768);
    k_convB<<<256, 256, 0, stream>>>(W2, BT2h, BT2l, 256);

    // CSR by dst
    (void)hipMemsetAsync(counts, 0, (size_t)N * 4, stream);
    k_degree<<<eb, 256, 0, stream>>>(dstA, counts, E);
    k_part<<<nb, 256, 0, stream>>>(counts, psum, N);
    k_scan_part<<<1, 256, 0, stream>>>(psum, nb, rowptr + N);
    k_rowptr<<<nb, 256, 0, stream>>>(counts, psum, rowptr, cursor, N);
    k_scatter<<<eb, 256, 0, stream>>>(srcA, dstA, cursor, colbuf, E);

    // layer 1
    k_gemm_f32A<<<gg, 256, 0, stream>>>(x, BT1h, BT1l, bufH, N, 768);
    k_att<<<nb4, 256, 0, stream>>>(bufH, as1, ad1, asrc, adst, N);
    k_alpha<<<nb4, 256, 0, stream>>>(asrc, adst, rowptr, colbuf, walpha, wselfv, winvv, N);
    k_gather<<<nb4, 256, 0, stream>>>(bufH, walpha, wselfv, winvv, rowptr, colbuf, b1,
                                      nullptr, X2h, X2l, nullptr, nullptr, nullptr, N);

    // layer 2
    k_gemm_bf16A<<<gg, 256, 0, stream>>>(X2h, X2l, BT2h, BT2l, bufH, N, 256);
    k_att<<<nb4, 256, 0, stream>>>(bufH, as2, ad2, asrc, adst, N);
    k_alpha<<<nb4, 256, 0, stream>>>(asrc, adst, rowptr, colbuf, walpha, wselfv, winvv, N);
    k_gather<<<nb4, 256, 0, stream>>>(bufH, walpha, wselfv, winvv, rowptr, colbuf, b2,
                                      bufX, nullptr, nullptr, gw, gb, gate, N);

    // global attention
    k_pmax<<<64, 256, 0, stream>>>(gate, N, pmax);
    k_gmid<<<1, 256, 0, stream>>>(pmax, 64, scal, gout);
    k_gout<<<256, 256, 0, stream>>>(bufX, gate, scal, gout, N);
    k_final<<<1, 256, 0, stream>>>(gout, scal, out);
}

// Round 6
// 671.538 us; speedup vs baseline: 1.8435x; 1.1520x over previous
//
#include <hip/hip_runtime.h>

#define WAVE 64
#define LRELU(x) ((x) > 0.0f ? (x) : 0.2f * (x))

typedef __attribute__((ext_vector_type(8))) short bf16x8;
typedef __attribute__((ext_vector_type(4))) float f32x4;

__device__ __forceinline__ void gld16(const void* g, void* l) {
    __builtin_amdgcn_global_load_lds((const __attribute__((address_space(1))) unsigned int*)g,
                                     (__attribute__((address_space(3))) unsigned int*)l,
                                     16, 0, 0);
}

__device__ __forceinline__ unsigned short f2bf_hi(float f) {
    unsigned u = __builtin_bit_cast(unsigned, f);
    u += 0x7FFF + ((u >> 16) & 1);
    return (unsigned short)(u >> 16);
}

__device__ __forceinline__ float4 bf4_to_f32(ushort4 v) {
    float4 r;
    r.x = __builtin_bit_cast(float, (unsigned)v.x << 16);
    r.y = __builtin_bit_cast(float, (unsigned)v.y << 16);
    r.z = __builtin_bit_cast(float, (unsigned)v.z << 16);
    r.w = __builtin_bit_cast(float, (unsigned)v.w << 16);
    return r;
}

// split 8 fp32 -> bf16 hi/lo (3-term Ootomo split, validated rounds 2/4/5)
__device__ __forceinline__ void split8(f32x4 a, f32x4 b, bf16x8& hi, bf16x8& lo) {
    float f[8] = {a[0], a[1], a[2], a[3], b[0], b[1], b[2], b[3]};
#pragma unroll
    for (int e = 0; e < 8; e++) {
        unsigned u = __builtin_bit_cast(unsigned, f[e]);
        unsigned t = u + 0x7FFF + ((u >> 16) & 1);
        float hf = __builtin_bit_cast(float, t & 0xFFFF0000u);
        float fl = f[e] - hf;
        unsigned u2 = __builtin_bit_cast(unsigned, fl);
        unsigned t2 = u2 + 0x7FFF + ((u2 >> 16) & 1);
        hi[e] = (short)(t >> 16);
        lo[e] = (short)(t2 >> 16);
    }
}

// ============ GEMM layer1: C[M,256] = A_f32[M,K] @ B; B = BT hi/lo [256][K] bf16.
// 128x128 tile, 4 waves. A: register-prefetched fp32, split once at staging,
// fragment-major LDS (conflict-free). B via gld16. Epilogue writes fp32 C + bf16 Cb.
__global__ __launch_bounds__(256) void k_gemm_f32A(const float* __restrict__ A,
                                                   const unsigned short* __restrict__ Bh,
                                                   const unsigned short* __restrict__ Bl,
                                                   float* __restrict__ C,
                                                   unsigned short* __restrict__ Cb,
                                                   int M, int K) {
    __shared__ char smem[32768];
    char* SAH = smem;            // A hi: 32 fragments (8 mt x 4 q) x 256B
    char* SAL = smem + 8192;     // A lo
    char* SBH = smem + 16384;    // B hi: 8 chunks x 1KB (16 rows x 64B)
    char* SBL = smem + 24576;    // B lo

    const int tid = threadIdx.x, lane = tid & 63, w = tid >> 6;
    const int m16 = lane & 15, q = lane >> 4;
    const int row0 = blockIdx.x * 128, col0 = blockIdx.y * 128;

    f32x4 acc[4][4];
#pragma unroll
    for (int i = 0; i < 4; i++)
#pragma unroll
        for (int j = 0; j < 4; j++) acc[i][j] = (f32x4){0.f, 0.f, 0.f, 0.f};

    // A staging: thread owns row tid>>1, k-half tid&1
    const int s_row = tid >> 1;
    const int s_mt  = s_row >> 4, s_m16 = s_row & 15;
    const int s_q0  = (tid & 1) * 2;
    int s_grow = row0 + s_row;
    if (s_grow > M - 1) s_grow = M - 1;
    const f32x4* aptr = (const f32x4*)&A[(size_t)s_grow * K] + (tid & 1) * 4;
    const int s_off = (s_mt * 4 + s_q0) * 256 + s_m16 * 16;

    const int b_rloc = lane >> 2;
    const int b_kb   = (lane & 3) * 16;

    f32x4 pre0 = aptr[0], pre1 = aptr[1], pre2 = aptr[2], pre3 = aptr[3];

    for (int k0 = 0; k0 < K; k0 += 32) {
#pragma unroll
        for (int s = 0; s < 2; s++) {
            int c = w * 2 + s;
            int brow = col0 + c * 16 + b_rloc;
            gld16((const char*)Bh + ((size_t)brow * K + k0) * 2 + b_kb, SBH + c * 1024);
            gld16((const char*)Bl + ((size_t)brow * K + k0) * 2 + b_kb, SBL + c * 1024);
        }
        {
            bf16x8 h0, l0, h1, l1;
            split8(pre0, pre1, h0, l0);
            split8(pre2, pre3, h1, l1);
            *(bf16x8*)(SAH + s_off)       = h0;
            *(bf16x8*)(SAL + s_off)       = l0;
            *(bf16x8*)(SAH + s_off + 256) = h1;
            *(bf16x8*)(SAL + s_off + 256) = l1;
        }
        __syncthreads();

        if (k0 + 32 < K) {
            aptr += 8;
            pre0 = aptr[0]; pre1 = aptr[1]; pre2 = aptr[2]; pre3 = aptr[3];
        }

        bf16x8 bh[4], bl[4];
#pragma unroll
        for (int nt = 0; nt < 4; nt++) {
            int r = (w & 1) * 64 + nt * 16 + m16;
            bh[nt] = *(bf16x8*)(SBH + r * 64 + q * 16);
            bl[nt] = *(bf16x8*)(SBL + r * 64 + q * 16);
        }
#pragma unroll
        for (int mt = 0; mt < 4; mt++) {
            int frag = ((w >> 1) * 4 + mt) * 4 + q;
            bf16x8 ah = *(bf16x8*)(SAH + frag * 256 + m16 * 16);
            bf16x8 al = *(bf16x8*)(SAL + frag * 256 + m16 * 16);
#pragma unroll
            for (int nt = 0; nt < 4; nt++) {
                acc[mt][nt] = __builtin_amdgcn_mfma_f32_16x16x32_bf16(ah, bh[nt], acc[mt][nt], 0, 0, 0);
                acc[mt][nt] = __builtin_amdgcn_mfma_f32_16x16x32_bf16(ah, bl[nt], acc[mt][nt], 0, 0, 0);
                acc[mt][nt] = __builtin_amdgcn_mfma_f32_16x16x32_bf16(al, bh[nt], acc[mt][nt], 0, 0, 0);
            }
        }
        __syncthreads();
    }

    const int rbase = row0 + (w >> 1) * 64;
    const int cbase = col0 + (w & 1) * 64;
#pragma unroll
    for (int mt = 0; mt < 4; mt++)
#pragma unroll
        for (int r = 0; r < 4; r++) {
            int row = rbase + mt * 16 + q * 4 + r;
            if (row < M) {
#pragma unroll
                for (int nt = 0; nt < 4; nt++) {
                    float v = acc[mt][nt][r];
                    C[(size_t)row * 256 + cbase + nt * 16 + m16] = v;
                    Cb[(size_t)row * 256 + cbase + nt * 16 + m16] = f2bf_hi(v);
                }
            }
        }
}

// ============ GEMM layer2: A pre-split bf16 planes [Mpad][K].
__global__ __launch_bounds__(256) void k_gemm_bf16A(const unsigned short* __restrict__ Ah,
                                                    const unsigned short* __restrict__ Al,
                                                    const unsigned short* __restrict__ Bh,
                                                    const unsigned short* __restrict__ Bl,
                                                    float* __restrict__ C,
                                                    unsigned short* __restrict__ Cb,
                                                    int M, int K) {
    __shared__ char smem[32768];
    char* SAH = smem;
    char* SAL = smem + 8192;
    char* SBH = smem + 16384;
    char* SBL = smem + 24576;

    const int tid = threadIdx.x, lane = tid & 63, w = tid >> 6;
    const int m16 = lane & 15, q = lane >> 4;
    const int row0 = blockIdx.x * 128, col0 = blockIdx.y * 128;

    f32x4 acc[4][4];
#pragma unroll
    for (int i = 0; i < 4; i++)
#pragma unroll
        for (int j = 0; j < 4; j++) acc[i][j] = (f32x4){0.f, 0.f, 0.f, 0.f};

    const int rloc = lane >> 2;
    const int kb   = (lane & 3) * 16;

    for (int k0 = 0; k0 < K; k0 += 32) {
#pragma unroll
        for (int s = 0; s < 2; s++) {
            int c = w * 2 + s;
            int arow = row0 + c * 16 + rloc;
            int brow = col0 + c * 16 + rloc;
            gld16((const char*)Ah + ((size_t)arow * K + k0) * 2 + kb, SAH + c * 1024);
            gld16((const char*)Al + ((size_t)arow * K + k0) * 2 + kb, SAL + c * 1024);
            gld16((const char*)Bh + ((size_t)brow * K + k0) * 2 + kb, SBH + c * 1024);
            gld16((const char*)Bl + ((size_t)brow * K + k0) * 2 + kb, SBL + c * 1024);
        }
        __syncthreads();

        bf16x8 bh[4], bl[4];
#pragma unroll
        for (int nt = 0; nt < 4; nt++) {
            int r = (w & 1) * 64 + nt * 16 + m16;
            bh[nt] = *(bf16x8*)(SBH + r * 64 + q * 16);
            bl[nt] = *(bf16x8*)(SBL + r * 64 + q * 16);
        }
#pragma unroll
        for (int mt = 0; mt < 4; mt++) {
            int r = (w >> 1) * 64 + mt * 16 + m16;
            bf16x8 ah = *(bf16x8*)(SAH + r * 64 + q * 16);
            bf16x8 al = *(bf16x8*)(SAL + r * 64 + q * 16);
#pragma unroll
            for (int nt = 0; nt < 4; nt++) {
                acc[mt][nt] = __builtin_amdgcn_mfma_f32_16x16x32_bf16(ah, bh[nt], acc[mt][nt], 0, 0, 0);
                acc[mt][nt] = __builtin_amdgcn_mfma_f32_16x16x32_bf16(ah, bl[nt], acc[mt][nt], 0, 0, 0);
                acc[mt][nt] = __builtin_amdgcn_mfma_f32_16x16x32_bf16(al, bh[nt], acc[mt][nt], 0, 0, 0);
            }
        }
        __syncthreads();
    }

    const int rbase = row0 + (w >> 1) * 64;
    const int cbase = col0 + (w & 1) * 64;
#pragma unroll
    for (int mt = 0; mt < 4; mt++)
#pragma unroll
        for (int r = 0; r < 4; r++) {
            int row = rbase + mt * 16 + q * 4 + r;
            if (row < M) {
#pragma unroll
                for (int nt = 0; nt < 4; nt++) {
                    float v = acc[mt][nt][r];
                    C[(size_t)row * 256 + cbase + nt * 16 + m16] = v;
                    Cb[(size_t)row * 256 + cbase + nt * 16 + m16] = f2bf_hi(v);
                }
            }
        }
}

// ---------------- W [K][256] fp32 -> BThi/BTlo [256][K] bf16 (transpose + split)
__global__ __launch_bounds__(256) void k_convB(const float* __restrict__ W,
                                               unsigned short* __restrict__ BThi,
                                               unsigned short* __restrict__ BTlo, int K) {
    int idx = blockIdx.x * 256 + threadIdx.x;
    int k = idx >> 8, n = idx & 255;
    if (k >= K) return;
    float f = W[(size_t)k * 256 + n];
    unsigned u = __builtin_bit_cast(unsigned, f);
    unsigned t = u + 0x7FFF + ((u >> 16) & 1);
    float hf = __builtin_bit_cast(float, t & 0xFFFF0000u);
    unsigned short lb = f2bf_hi(f - hf);
    BThi[(size_t)n * K + k] = (unsigned short)(t >> 16);
    BTlo[(size_t)n * K + k] = lb;
}

// ---------------- per-node dots (fp32 h): asrc[i] = h[i,:].as, adst[i] = h[i,:].ad
__global__ __launch_bounds__(256) void k_att(const float* __restrict__ h,
                                             const float* __restrict__ att_s,
                                             const float* __restrict__ att_d,
                                             float* __restrict__ asrc,
                                             float* __restrict__ adst, int N) {
    int wid = threadIdx.x >> 6;
    int lane = threadIdx.x & 63;
    int node = blockIdx.x * 4 + wid;
    if (node >= N) return;
    float4 hv = *(const float4*)&h[(size_t)node * 256 + lane * 4];
    float4 sv = *(const float4*)&att_s[lane * 4];
    float4 dv = *(const float4*)&att_d[lane * 4];
    float s = hv.x * sv.x + hv.y * sv.y + hv.z * sv.z + hv.w * sv.w;
    float d = hv.x * dv.x + hv.y * dv.y + hv.z * dv.z + hv.w * dv.w;
#pragma unroll
    for (int off = 32; off; off >>= 1) {
        s += __shfl_xor(s, off);
        d += __shfl_xor(d, off);
    }
    if (lane == 0) { asrc[node] = s; adst[node] = d; }
}

// ---------------- CSR build
__global__ __launch_bounds__(256) void k_degree(const int* __restrict__ dst,
                                                int* __restrict__ counts, int E) {
    int e = blockIdx.x * 256 + threadIdx.x;
    if (e < E) atomicAdd(&counts[dst[e]], 1);
}

__global__ __launch_bounds__(256) void k_part(const int* __restrict__ counts,
                                              int* __restrict__ psum, int N) {
    __shared__ int red[256];
    int tid = threadIdx.x;
    int i = blockIdx.x * 256 + tid;
    red[tid] = (i < N) ? counts[i] : 0;
    __syncthreads();
    for (int off = 128; off; off >>= 1) {
        if (tid < off) red[tid] += red[tid + off];
        __syncthreads();
    }
    if (tid == 0) psum[blockIdx.x] = red[0];
}

__global__ __launch_bounds__(256) void k_scan_part(int* __restrict__ psum, int nb,
                                                   int* __restrict__ total_out) {
    __shared__ int s[256];
    int tid = threadIdx.x;
    int v = (tid < nb) ? psum[tid] : 0;
    s[tid] = v;
    __syncthreads();
    for (int off = 1; off < 256; off <<= 1) {
        int t = (tid >= off) ? s[tid - off] : 0;
        __syncthreads();
        s[tid] += t;
        __syncthreads();
    }
    if (tid < nb) psum[tid] = s[tid] - v;
    if (tid == 255) *total_out = s[255];
}

__global__ __launch_bounds__(256) void k_rowptr(const int* __restrict__ counts,
                                                const int* __restrict__ psum,
                                                int* __restrict__ rowptr,
                                                int* __restrict__ cursor, int N) {
    __shared__ int s[256];
    int tid = threadIdx.x;
    int i = blockIdx.x * 256 + tid;
    int v = (i < N) ? counts[i] : 0;
    s[tid] = v;
    __syncthreads();
    for (int off = 1; off < 256; off <<= 1) {
        int t = (tid >= off) ? s[tid - off] : 0;
        __syncthreads();
        s[tid] += t;
        __syncthreads();
    }
    if (i < N) {
        int excl = psum[blockIdx.x] + s[tid] - v;
        rowptr[i] = excl;
        cursor[i] = excl;
    }
}

__global__ __launch_bounds__(256) void k_scatter(const int* __restrict__ src,
                                                 const int* __restrict__ dst,
                                                 int* __restrict__ cursor,
                                                 int* __restrict__ col, int E) {
    int e = blockIdx.x * 256 + threadIdx.x;
    if (e < E) {
        int p = atomicAdd(&cursor[dst[e]], 1);
        col[p] = src[e];
    }
}

// ---------------- phase 1: per-edge softmax weights (wave per node)
__global__ __launch_bounds__(256) void k_alpha(const float* __restrict__ asrc,
                                               const float* __restrict__ adst,
                                               const int* __restrict__ rowptr,
                                               const int* __restrict__ col,
                                               float* __restrict__ walpha,
                                               float* __restrict__ wselfv,
                                               float* __restrict__ winvv, int N) {
    int wid = threadIdx.x >> 6;
    int lane = threadIdx.x & 63;
    int node = blockIdx.x * 4 + wid;
    if (node >= N) return;
    int start = rowptr[node], end = rowptr[node + 1];
    float ad = adst[node];
    float eself = asrc[node] + ad;
    eself = LRELU(eself);
    float m = eself;
    for (int j = start + lane; j < end; j += WAVE) {
        float e = asrc[col[j]] + ad;
        e = LRELU(e);
        m = fmaxf(m, e);
    }
#pragma unroll
    for (int off = 32; off; off >>= 1) m = fmaxf(m, __shfl_xor(m, off));
    float sum = 0.f;
    for (int j = start + lane; j < end; j += WAVE) {
        float e = asrc[col[j]] + ad;
        e = LRELU(e);
        float wgt = __expf(e - m);
        walpha[j] = wgt;
        sum += wgt;
    }
#pragma unroll
    for (int off = 32; off; off >>= 1) sum += __shfl_xor(sum, off);
    if (lane == 0) {
        float ws = __expf(eself - m);
        wselfv[node] = ws;
        winvv[node] = 1.0f / (sum + ws + 1e-16f);
    }
}

// ---------------- phase 2: weighted gather from bf16 table (wave per node), unroll x4.
__global__ __launch_bounds__(256) void k_gather(const unsigned short* __restrict__ hb,
                                                const float* __restrict__ walpha,
                                                const float* __restrict__ wselfv,
                                                const float* __restrict__ winvv,
                                                const int* __restrict__ rowptr,
                                                const int* __restrict__ col,
                                                const float* __restrict__ bias,
                                                float* __restrict__ outf,
                                                unsigned short* __restrict__ outh,
                                                unsigned short* __restrict__ outl,
                                                const float* __restrict__ gw,
                                                const float* __restrict__ gb,
                                                float* __restrict__ gatep, int N) {
    int wid = threadIdx.x >> 6;
    int lane = threadIdx.x & 63;
    int node = blockIdx.x * 4 + wid;
    if (node >= N) return;
    int j = rowptr[node], end = rowptr[node + 1];
    float ws = wselfv[node];
    float4 hv = bf4_to_f32(*(const ushort4*)&hb[(size_t)node * 256 + lane * 4]);
    float ax = ws * hv.x, ay = ws * hv.y, az = ws * hv.z, aw = ws * hv.w;
    for (; j + 4 <= end; j += 4) {
        int s0 = col[j], s1 = col[j + 1], s2 = col[j + 2], s3 = col[j + 3];
        float w0 = walpha[j], w1 = walpha[j + 1], w2 = walpha[j + 2], w3 = walpha[j + 3];
        float4 h0 = bf4_to_f32(*(const ushort4*)&hb[(size_t)s0 * 256 + lane * 4]);
        float4 h1 = bf4_to_f32(*(const ushort4*)&hb[(size_t)s1 * 256 + lane * 4]);
        float4 h2 = bf4_to_f32(*(const ushort4*)&hb[(size_t)s2 * 256 + lane * 4]);
        float4 h3 = bf4_to_f32(*(const ushort4*)&hb[(size_t)s3 * 256 + lane * 4]);
        ax = fmaf(w0, h0.x, fmaf(w1, h1.x, fmaf(w2, h2.x, fmaf(w3, h3.x, ax))));
        ay = fmaf(w0, h0.y, fmaf(w1, h1.y, fmaf(w2, h2.y, fmaf(w3, h3.y, ay))));
        az = fmaf(w0, h0.z, fmaf(w1, h1.z, fmaf(w2, h2.z, fmaf(w3, h3.z, az))));
        aw = fmaf(w0, h0.w, fmaf(w1, h1.w, fmaf(w2, h2.w, fmaf(w3, h3.w, aw))));
    }
    for (; j < end; j++) {
        int s = col[j];
        float wgt = walpha[j];
        float4 hx = bf4_to_f32(*(const ushort4*)&hb[(size_t)s * 256 + lane * 4]);
        ax = fmaf(wgt, hx.x, ax); ay = fmaf(wgt, hx.y, ay);
        az = fmaf(wgt, hx.z, az); aw = fmaf(wgt, hx.w, aw);
    }
    float inv = winvv[node];
    float4 bv = *(const float4*)&bias[lane * 4];
    float ox = fmaxf(fmaf(ax, inv, bv.x), 0.0f);
    float oy = fmaxf(fmaf(ay, inv, bv.y), 0.0f);
    float oz = fmaxf(fmaf(az, inv, bv.z), 0.0f);
    float ow = fmaxf(fmaf(aw, inv, bv.w), 0.0f);
    if (outf) {
        float4 o = make_float4(ox, oy, oz, ow);
        *(float4*)&outf[(size_t)node * 256 + lane * 4] = o;
    }
    if (outh) {
        float of[4] = {ox, oy, oz, ow};
        unsigned long long ph = 0, pl = 0;
#pragma unroll
        for (int e = 0; e < 4; e++) {
            unsigned u = __builtin_bit_cast(unsigned, of[e]);
            unsigned t = u + 0x7FFF + ((u >> 16) & 1);
            float hf = __builtin_bit_cast(float, t & 0xFFFF0000u);
            float fl = of[e] - hf;
            unsigned u2 = __builtin_bit_cast(unsigned, fl);
            unsigned t2 = u2 + 0x7FFF + ((u2 >> 16) & 1);
            ph |= ((unsigned long long)(t >> 16)) << (16 * e);
            pl |= ((unsigned long long)(t2 >> 16)) << (16 * e);
        }
        *(unsigned long long*)&outh[(size_t)node * 256 + lane * 4] = ph;
        *(unsigned long long*)&outl[(size_t)node * 256 + lane * 4] = pl;
    }
    if (gatep) {
        float4 gv = *(const float4*)&gw[lane * 4];
        float s = ox * gv.x + oy * gv.y + oz * gv.z + ow * gv.w;
#pragma unroll
        for (int off = 32; off; off >>= 1) s += __shfl_xor(s, off);
        if (lane == 0) gatep[node] = s + gb[0];
    }
}

// ---------------- global attention
__global__ __launch_bounds__(256) void k_pmax(const float* __restrict__ gate, int N,
                                              float* __restrict__ pmax) {
    __shared__ float red[256];
    int tid = threadIdx.x;
    float m = -3.0e38f;
    for (int i = blockIdx.x * 256 + tid; i < N; i += gridDim.x * 256) m = fmaxf(m, gate[i]);
    red[tid] = m;
    __syncthreads();
    for (int off = 128; off; off >>= 1) {
        if (tid < off) red[tid] = fmaxf(red[tid], red[tid + off]);
        __syncthreads();
    }
    if (tid == 0) pmax[blockIdx.x] = red[0];
}

__global__ __launch_bounds__(256) void k_gmid(const float* __restrict__ pmax, int nb,
                                              float* __restrict__ scal,
                                              float* __restrict__ gout) {
    __shared__ float red[256];
    int tid = threadIdx.x;
    red[tid] = (tid < nb) ? pmax[tid] : -3.0e38f;
    __syncthreads();
    for (int off = 128; off; off >>= 1) {
        if (tid < off) red[tid] = fmaxf(red[tid], red[tid + off]);
        __syncthreads();
    }
    if (tid == 0) { scal[0] = red[0]; scal[1] = 0.0f; }
    gout[tid] = 0.0f;
}

__global__ __launch_bounds__(256) void k_gout(const float* __restrict__ h,
                                              const float* __restrict__ gate,
                                              float* __restrict__ scal_rw,
                                              float* __restrict__ gout, int N) {
    int f = threadIdx.x;
    float gmax = scal_rw[0];
    float acc = 0.0f, sumw = 0.0f;
    for (int i = blockIdx.x; i < N; i += gridDim.x) {
        float w = __expf(gate[i] - gmax);
        acc = fmaf(w, h[(size_t)i * 256 + f], acc);
        sumw += w;
    }
    atomicAdd(&gout[f], acc);
    if (f == 0) atomicAdd(&scal_rw[1], sumw);
}

__global__ __launch_bounds__(256) void k_final(const float* __restrict__ gout,
                                               const float* __restrict__ scal,
                                               float* __restrict__ out) {
    int f = threadIdx.x;
    out[f] = gout[f] / scal[1];
}

extern "C" void kernel_launch(void* const* d_in, const int* in_sizes, int n_in,
                              void* d_out, int out_size, void* d_ws, size_t ws_size,
                              hipStream_t stream) {
    const float* x   = (const float*)d_in[0];
    const int*   ei  = (const int*)d_in[1];
    const float* W1  = (const float*)d_in[2];
    const float* b1  = (const float*)d_in[3];
    const float* as1 = (const float*)d_in[4];
    const float* ad1 = (const float*)d_in[5];
    const float* W2  = (const float*)d_in[6];
    const float* b2  = (const float*)d_in[7];
    const float* as2 = (const float*)d_in[8];
    const float* ad2 = (const float*)d_in[9];
    const float* gw  = (const float*)d_in[10];
    const float* gb  = (const float*)d_in[11];
    float* out = (float*)d_out;

    const int N = in_sizes[0] / 768;   // 50000
    const int E = in_sizes[1] / 2;     // 800000
    const int Mpad = (N + 127) & ~127; // 50048
    const int* srcA = ei;
    const int* dstA = ei + E;

    char* w = (char*)d_ws;
    auto alloc = [&](size_t bytes) -> void* {
        void* p = (void*)w;
        w += (bytes + 255) & ~(size_t)255;
        return p;
    };
    float* bufH = (float*)alloc((size_t)N * 256 * 4);              // fp32 h (both layers)
    unsigned short* bufHb = (unsigned short*)alloc((size_t)N * 256 * 2);  // bf16 h replica
    unsigned short* X2h = (unsigned short*)alloc((size_t)Mpad * 256 * 2);
    unsigned short* X2l = (unsigned short*)alloc((size_t)Mpad * 256 * 2);
    float* bufX = (float*)X2h;  // alias: X2 planes dead after GEMM2
    float* asrc   = (float*)alloc((size_t)N * 4);
    float* adst   = (float*)alloc((size_t)N * 4);
    float* gate   = (float*)alloc((size_t)N * 4);
    float* wselfv = (float*)alloc((size_t)N * 4);
    float* winvv  = (float*)alloc((size_t)N * 4);
    int*   counts = (int*)alloc((size_t)N * 4);
    int*   rowptr = (int*)alloc((size_t)(N + 1) * 4);
    int*   cursor = (int*)alloc((size_t)N * 4);
    int*   colbuf = (int*)alloc((size_t)E * 4);
    float* walpha = (float*)alloc((size_t)E * 4);
    int*   psum   = (int*)alloc(256 * 4);
    float* pmax   = (float*)alloc(256 * 4);
    float* scal   = (float*)alloc(8 * 4);
    float* gout   = (float*)alloc(256 * 4);
    unsigned short* BT1h = (unsigned short*)alloc((size_t)256 * 768 * 2);
    unsigned short* BT1l = (unsigned short*)alloc((size_t)256 * 768 * 2);
    unsigned short* BT2h = (unsigned short*)alloc((size_t)256 * 256 * 2);
    unsigned short* BT2l = (unsigned short*)alloc((size_t)256 * 256 * 2);

    const int eb  = (E + 255) / 256;
    const int nb4 = (N + 3) / 4;
    const int nb  = (N + 255) / 256;
    const dim3 gg(Mpad / 128, 2);

    // weight split/transpose
    k_convB<<<768, 256, 0, stream>>>(W1, BT1h, BT1l, 768);
    k_convB<<<256, 256, 0, stream>>>(W2, BT2h, BT2l, 256);

    // CSR by dst
    (void)hipMemsetAsync(counts, 0, (size_t)N * 4, stream);
    k_degree<<<eb, 256, 0, stream>>>(dstA, counts, E);
    k_part<<<nb, 256, 0, stream>>>(counts, psum, N);
    k_scan_part<<<1, 256, 0, stream>>>(psum, nb, rowptr + N);
    k_rowptr<<<nb, 256, 0, stream>>>(counts, psum, rowptr, cursor, N);
    k_scatter<<<eb, 256, 0, stream>>>(srcA, dstA, cursor, colbuf, E);

    // layer 1
    k_gemm_f32A<<<gg, 256, 0, stream>>>(x, BT1h, BT1l, bufH, bufHb, N, 768);
    k_att<<<nb4, 256, 0, stream>>>(bufH, as1, ad1, asrc, adst, N);
    k_alpha<<<nb4, 256, 0, stream>>>(asrc, adst, rowptr, colbuf, walpha, wselfv, winvv, N);
    k_gather<<<nb4, 256, 0, stream>>>(bufHb, walpha, wselfv, winvv, rowptr, colbuf, b1,
                                      nullptr, X2h, X2l, nullptr, nullptr, nullptr, N);

    // layer 2
    k_gemm_bf16A<<<gg, 256, 0, stream>>>(X2h, X2l, BT2h, BT2l, bufH, bufHb, N, 256);
    k_att<<<nb4, 256, 0, stream>>>(bufH, as2, ad2, asrc, adst, N);
    k_alpha<<<nb4, 256, 0, stream>>>(asrc, adst, rowptr, colbuf, walpha, wselfv, winvv, N);
    k_gather<<<nb4, 256, 0, stream>>>(bufHb, walpha, wselfv, winvv, rowptr, colbuf, b2,
                                      bufX, nullptr, nullptr, gw, gb, gate, N);

    // global attention
    k_pmax<<<64, 256, 0, stream>>>(gate, N, pmax);
    k_gmid<<<1, 256, 0, stream>>>(pmax, 64, scal, gout);
    k_gout<<<256, 256, 0, stream>>>(bufX, gate, scal, gout, N);
    k_final<<<1, 256, 0, stream>>>(gout, scal, out);
}

// Round 7
// 629.919 us; speedup vs baseline: 1.9653x; 1.0661x over previous
//
#include <hip/hip_runtime.h>

#define WAVE 64
#define LRELU(x) ((x) > 0.0f ? (x) : 0.2f * (x))

typedef __attribute__((ext_vector_type(8))) short bf16x8;
typedef __attribute__((ext_vector_type(4))) float f32x4;

__device__ __forceinline__ void gld16(const void* g, void* l) {
    __builtin_amdgcn_global_load_lds((const __attribute__((address_space(1))) unsigned int*)g,
                                     (__attribute__((address_space(3))) unsigned int*)l,
                                     16, 0, 0);
}

__device__ __forceinline__ unsigned short f2bf_hi(float f) {
    unsigned u = __builtin_bit_cast(unsigned, f);
    u += 0x7FFF + ((u >> 16) & 1);
    return (unsigned short)(u >> 16);
}

__device__ __forceinline__ float4 bf4_to_f32(ushort4 v) {
    float4 r;
    r.x = __builtin_bit_cast(float, (unsigned)v.x << 16);
    r.y = __builtin_bit_cast(float, (unsigned)v.y << 16);
    r.z = __builtin_bit_cast(float, (unsigned)v.z << 16);
    r.w = __builtin_bit_cast(float, (unsigned)v.w << 16);
    return r;
}

// truncation-hi split: hi = top16(f), lo = rne_bf16(f - hi). ~7 ops/elem vs 11 for
// rne-hi; product error still ~2^-16 rel (lo absorbs hi truncation).
__device__ __forceinline__ void split8(f32x4 a, f32x4 b, bf16x8& hi, bf16x8& lo) {
    float f[8] = {a[0], a[1], a[2], a[3], b[0], b[1], b[2], b[3]};
#pragma unroll
    for (int e = 0; e < 8; e++) {
        unsigned u = __builtin_bit_cast(unsigned, f[e]);
        float hf = __builtin_bit_cast(float, u & 0xFFFF0000u);
        float fl = f[e] - hf;
        unsigned u2 = __builtin_bit_cast(unsigned, fl);
        unsigned t2 = u2 + 0x7FFF + ((u2 >> 16) & 1);
        hi[e] = (short)(u >> 16);
        lo[e] = (short)(t2 >> 16);
    }
}

// ============ GEMM layer1: Cb_bf16[M,256] = bf16(A_f32[M,K] @ B); fused att dots.
// 128x128 tile, 4 waves. A register-prefetched, split at staging, fragment-major LDS.
// Epilogue: bf16 Cb store + asrc/adst row-dot atomics (replaces k_att + fp32 C).
__global__ __launch_bounds__(256) void k_gemm_f32A(const float* __restrict__ A,
                                                   const unsigned short* __restrict__ Bh,
                                                   const unsigned short* __restrict__ Bl,
                                                   unsigned short* __restrict__ Cb,
                                                   float* __restrict__ asrc,
                                                   float* __restrict__ adst,
                                                   const float* __restrict__ att_s,
                                                   const float* __restrict__ att_d,
                                                   int M, int K) {
    __shared__ char smem[32768];
    char* SAH = smem;            // A hi: 32 fragments (8 mt x 4 q) x 256B
    char* SAL = smem + 8192;     // A lo
    char* SBH = smem + 16384;    // B hi: 8 chunks x 1KB
    char* SBL = smem + 24576;    // B lo

    const int tid = threadIdx.x, lane = tid & 63, w = tid >> 6;
    const int m16 = lane & 15, q = lane >> 4;
    const int row0 = blockIdx.x * 128, col0 = blockIdx.y * 128;

    f32x4 acc[4][4];
#pragma unroll
    for (int i = 0; i < 4; i++)
#pragma unroll
        for (int j = 0; j < 4; j++) acc[i][j] = (f32x4){0.f, 0.f, 0.f, 0.f};

    const int s_row = tid >> 1;
    const int s_mt  = s_row >> 4, s_m16 = s_row & 15;
    const int s_q0  = (tid & 1) * 2;
    int s_grow = row0 + s_row;
    if (s_grow > M - 1) s_grow = M - 1;
    const f32x4* aptr = (const f32x4*)&A[(size_t)s_grow * K] + (tid & 1) * 4;
    const int s_off = (s_mt * 4 + s_q0) * 256 + s_m16 * 16;

    const int b_rloc = lane >> 2;
    const int b_kb   = (lane & 3) * 16;

    f32x4 pre0 = aptr[0], pre1 = aptr[1], pre2 = aptr[2], pre3 = aptr[3];

    for (int k0 = 0; k0 < K; k0 += 32) {
#pragma unroll
        for (int s = 0; s < 2; s++) {
            int c = w * 2 + s;
            int brow = col0 + c * 16 + b_rloc;
            gld16((const char*)Bh + ((size_t)brow * K + k0) * 2 + b_kb, SBH + c * 1024);
            gld16((const char*)Bl + ((size_t)brow * K + k0) * 2 + b_kb, SBL + c * 1024);
        }
        {
            bf16x8 h0, l0, h1, l1;
            split8(pre0, pre1, h0, l0);
            split8(pre2, pre3, h1, l1);
            *(bf16x8*)(SAH + s_off)       = h0;
            *(bf16x8*)(SAL + s_off)       = l0;
            *(bf16x8*)(SAH + s_off + 256) = h1;
            *(bf16x8*)(SAL + s_off + 256) = l1;
        }
        __syncthreads();

        if (k0 + 32 < K) {
            aptr += 8;
            pre0 = aptr[0]; pre1 = aptr[1]; pre2 = aptr[2]; pre3 = aptr[3];
        }

        bf16x8 bh[4], bl[4];
#pragma unroll
        for (int nt = 0; nt < 4; nt++) {
            int r = (w & 1) * 64 + nt * 16 + m16;
            bh[nt] = *(bf16x8*)(SBH + r * 64 + q * 16);
            bl[nt] = *(bf16x8*)(SBL + r * 64 + q * 16);
        }
#pragma unroll
        for (int mt = 0; mt < 4; mt++) {
            int frag = ((w >> 1) * 4 + mt) * 4 + q;
            bf16x8 ah = *(bf16x8*)(SAH + frag * 256 + m16 * 16);
            bf16x8 al = *(bf16x8*)(SAL + frag * 256 + m16 * 16);
#pragma unroll
            for (int nt = 0; nt < 4; nt++) {
                acc[mt][nt] = __builtin_amdgcn_mfma_f32_16x16x32_bf16(ah, bh[nt], acc[mt][nt], 0, 0, 0);
                acc[mt][nt] = __builtin_amdgcn_mfma_f32_16x16x32_bf16(ah, bl[nt], acc[mt][nt], 0, 0, 0);
                acc[mt][nt] = __builtin_amdgcn_mfma_f32_16x16x32_bf16(al, bh[nt], acc[mt][nt], 0, 0, 0);
            }
        }
        __syncthreads();
    }

    const int rbase = row0 + (w >> 1) * 64;
    const int cbase = col0 + (w & 1) * 64;
    // bf16 store
#pragma unroll
    for (int mt = 0; mt < 4; mt++)
#pragma unroll
        for (int r = 0; r < 4; r++) {
            int row = rbase + mt * 16 + q * 4 + r;
            if (row < M) {
#pragma unroll
                for (int nt = 0; nt < 4; nt++)
                    Cb[(size_t)row * 256 + cbase + nt * 16 + m16] = f2bf_hi(acc[mt][nt][r]);
            }
        }
    // fused att dots: per-row partial over this block's 128 cols, atomic-accumulated
    float as_v[4], ad_v[4];
#pragma unroll
    for (int nt = 0; nt < 4; nt++) {
        as_v[nt] = att_s[cbase + nt * 16 + m16];
        ad_v[nt] = att_d[cbase + nt * 16 + m16];
    }
#pragma unroll
    for (int mt = 0; mt < 4; mt++)
#pragma unroll
        for (int r = 0; r < 4; r++) {
            float s = 0.f, d = 0.f;
#pragma unroll
            for (int nt = 0; nt < 4; nt++) {
                float v = acc[mt][nt][r];
                s = fmaf(v, as_v[nt], s);
                d = fmaf(v, ad_v[nt], d);
            }
#pragma unroll
            for (int off = 1; off < 16; off <<= 1) {
                s += __shfl_xor(s, off);
                d += __shfl_xor(d, off);
            }
            int row = rbase + mt * 16 + q * 4 + r;
            if (m16 == 0 && row < M) {
                atomicAdd(&asrc[row], s);
                atomicAdd(&adst[row], d);
            }
        }
}

// ============ GEMM layer2: A pre-split bf16 planes [Mpad][K]; same fused epilogue.
__global__ __launch_bounds__(256) void k_gemm_bf16A(const unsigned short* __restrict__ Ah,
                                                    const unsigned short* __restrict__ Al,
                                                    const unsigned short* __restrict__ Bh,
                                                    const unsigned short* __restrict__ Bl,
                                                    unsigned short* __restrict__ Cb,
                                                    float* __restrict__ asrc,
                                                    float* __restrict__ adst,
                                                    const float* __restrict__ att_s,
                                                    const float* __restrict__ att_d,
                                                    int M, int K) {
    __shared__ char smem[32768];
    char* SAH = smem;
    char* SAL = smem + 8192;
    char* SBH = smem + 16384;
    char* SBL = smem + 24576;

    const int tid = threadIdx.x, lane = tid & 63, w = tid >> 6;
    const int m16 = lane & 15, q = lane >> 4;
    const int row0 = blockIdx.x * 128, col0 = blockIdx.y * 128;

    f32x4 acc[4][4];
#pragma unroll
    for (int i = 0; i < 4; i++)
#pragma unroll
        for (int j = 0; j < 4; j++) acc[i][j] = (f32x4){0.f, 0.f, 0.f, 0.f};

    const int rloc = lane >> 2;
    const int kb   = (lane & 3) * 16;

    for (int k0 = 0; k0 < K; k0 += 32) {
#pragma unroll
        for (int s = 0; s < 2; s++) {
            int c = w * 2 + s;
            int arow = row0 + c * 16 + rloc;
            int brow = col0 + c * 16 + rloc;
            gld16((const char*)Ah + ((size_t)arow * K + k0) * 2 + kb, SAH + c * 1024);
            gld16((const char*)Al + ((size_t)arow * K + k0) * 2 + kb, SAL + c * 1024);
            gld16((const char*)Bh + ((size_t)brow * K + k0) * 2 + kb, SBH + c * 1024);
            gld16((const char*)Bl + ((size_t)brow * K + k0) * 2 + kb, SBL + c * 1024);
        }
        __syncthreads();

        bf16x8 bh[4], bl[4];
#pragma unroll
        for (int nt = 0; nt < 4; nt++) {
            int r = (w & 1) * 64 + nt * 16 + m16;
            bh[nt] = *(bf16x8*)(SBH + r * 64 + q * 16);
            bl[nt] = *(bf16x8*)(SBL + r * 64 + q * 16);
        }
#pragma unroll
        for (int mt = 0; mt < 4; mt++) {
            int r = (w >> 1) * 64 + mt * 16 + m16;
            bf16x8 ah = *(bf16x8*)(SAH + r * 64 + q * 16);
            bf16x8 al = *(bf16x8*)(SAL + r * 64 + q * 16);
#pragma unroll
            for (int nt = 0; nt < 4; nt++) {
                acc[mt][nt] = __builtin_amdgcn_mfma_f32_16x16x32_bf16(ah, bh[nt], acc[mt][nt], 0, 0, 0);
                acc[mt][nt] = __builtin_amdgcn_mfma_f32_16x16x32_bf16(ah, bl[nt], acc[mt][nt], 0, 0, 0);
                acc[mt][nt] = __builtin_amdgcn_mfma_f32_16x16x32_bf16(al, bh[nt], acc[mt][nt], 0, 0, 0);
            }
        }
        __syncthreads();
    }

    const int rbase = row0 + (w >> 1) * 64;
    const int cbase = col0 + (w & 1) * 64;
#pragma unroll
    for (int mt = 0; mt < 4; mt++)
#pragma unroll
        for (int r = 0; r < 4; r++) {
            int row = rbase + mt * 16 + q * 4 + r;
            if (row < M) {
#pragma unroll
                for (int nt = 0; nt < 4; nt++)
                    Cb[(size_t)row * 256 + cbase + nt * 16 + m16] = f2bf_hi(acc[mt][nt][r]);
            }
        }
    float as_v[4], ad_v[4];
#pragma unroll
    for (int nt = 0; nt < 4; nt++) {
        as_v[nt] = att_s[cbase + nt * 16 + m16];
        ad_v[nt] = att_d[cbase + nt * 16 + m16];
    }
#pragma unroll
    for (int mt = 0; mt < 4; mt++)
#pragma unroll
        for (int r = 0; r < 4; r++) {
            float s = 0.f, d = 0.f;
#pragma unroll
            for (int nt = 0; nt < 4; nt++) {
                float v = acc[mt][nt][r];
                s = fmaf(v, as_v[nt], s);
                d = fmaf(v, ad_v[nt], d);
            }
#pragma unroll
            for (int off = 1; off < 16; off <<= 1) {
                s += __shfl_xor(s, off);
                d += __shfl_xor(d, off);
            }
            int row = rbase + mt * 16 + q * 4 + r;
            if (m16 == 0 && row < M) {
                atomicAdd(&asrc[row], s);
                atomicAdd(&adst[row], d);
            }
        }
}

// ---------------- W [K][256] fp32 -> BThi/BTlo [256][K] bf16 (transpose + split)
__global__ __launch_bounds__(256) void k_convB(const float* __restrict__ W,
                                               unsigned short* __restrict__ BThi,
                                               unsigned short* __restrict__ BTlo, int K) {
    int idx = blockIdx.x * 256 + threadIdx.x;
    int k = idx >> 8, n = idx & 255;
    if (k >= K) return;
    float f = W[(size_t)k * 256 + n];
    unsigned u = __builtin_bit_cast(unsigned, f);
    unsigned t = u + 0x7FFF + ((u >> 16) & 1);
    float hf = __builtin_bit_cast(float, t & 0xFFFF0000u);
    unsigned short lb = f2bf_hi(f - hf);
    BThi[(size_t)n * K + k] = (unsigned short)(t >> 16);
    BTlo[(size_t)n * K + k] = lb;
}

// ---------------- CSR build
__global__ __launch_bounds__(256) void k_degree(const int* __restrict__ dst,
                                                int* __restrict__ counts, int E) {
    int e = blockIdx.x * 256 + threadIdx.x;
    if (e < E) atomicAdd(&counts[dst[e]], 1);
}

__global__ __launch_bounds__(256) void k_part(const int* __restrict__ counts,
                                              int* __restrict__ psum, int N) {
    __shared__ int red[256];
    int tid = threadIdx.x;
    int i = blockIdx.x * 256 + tid;
    red[tid] = (i < N) ? counts[i] : 0;
    __syncthreads();
    for (int off = 128; off; off >>= 1) {
        if (tid < off) red[tid] += red[tid + off];
        __syncthreads();
    }
    if (tid == 0) psum[blockIdx.x] = red[0];
}

__global__ __launch_bounds__(256) void k_scan_part(int* __restrict__ psum, int nb,
                                                   int* __restrict__ total_out) {
    __shared__ int s[256];
    int tid = threadIdx.x;
    int v = (tid < nb) ? psum[tid] : 0;
    s[tid] = v;
    __syncthreads();
    for (int off = 1; off < 256; off <<= 1) {
        int t = (tid >= off) ? s[tid - off] : 0;
        __syncthreads();
        s[tid] += t;
        __syncthreads();
    }
    if (tid < nb) psum[tid] = s[tid] - v;
    if (tid == 255) *total_out = s[255];
}

__global__ __launch_bounds__(256) void k_rowptr(const int* __restrict__ counts,
                                                const int* __restrict__ psum,
                                                int* __restrict__ rowptr,
                                                int* __restrict__ cursor, int N) {
    __shared__ int s[256];
    int tid = threadIdx.x;
    int i = blockIdx.x * 256 + tid;
    int v = (i < N) ? counts[i] : 0;
    s[tid] = v;
    __syncthreads();
    for (int off = 1; off < 256; off <<= 1) {
        int t = (tid >= off) ? s[tid - off] : 0;
        __syncthreads();
        s[tid] += t;
        __syncthreads();
    }
    if (i < N) {
        int excl = psum[blockIdx.x] + s[tid] - v;
        rowptr[i] = excl;
        cursor[i] = excl;
    }
}

__global__ __launch_bounds__(256) void k_scatter(const int* __restrict__ src,
                                                 const int* __restrict__ dst,
                                                 int* __restrict__ cursor,
                                                 int* __restrict__ col, int E) {
    int e = blockIdx.x * 256 + threadIdx.x;
    if (e < E) {
        int p = atomicAdd(&cursor[dst[e]], 1);
        col[p] = src[e];
    }
}

// ---------------- merged softmax+gather (wave per node):
// pass 1: max over in-edge scores; pass 2: recompute weights, gather bf16 rows.
__global__ __launch_bounds__(256) void k_edge(const unsigned short* __restrict__ hb,
                                              const float* __restrict__ asrc,
                                              const float* __restrict__ adst,
                                              const int* __restrict__ rowptr,
                                              const int* __restrict__ col,
                                              const float* __restrict__ bias,
                                              float* __restrict__ outf,
                                              unsigned short* __restrict__ outh,
                                              unsigned short* __restrict__ outl,
                                              const float* __restrict__ gw,
                                              const float* __restrict__ gb,
                                              float* __restrict__ gatep, int N) {
    int wid = threadIdx.x >> 6;
    int lane = threadIdx.x & 63;
    int node = blockIdx.x * 4 + wid;
    if (node >= N) return;
    int start = rowptr[node], end = rowptr[node + 1];
    float ad = adst[node];
    float eself = asrc[node] + ad;
    eself = LRELU(eself);
    float m = eself;
    for (int j = start + lane; j < end; j += WAVE) {
        float e = asrc[col[j]] + ad;
        e = LRELU(e);
        m = fmaxf(m, e);
    }
#pragma unroll
    for (int off = 32; off; off >>= 1) m = fmaxf(m, __shfl_xor(m, off));

    float wself = __expf(eself - m);
    float denom = wself;
    float4 hv = bf4_to_f32(*(const ushort4*)&hb[(size_t)node * 256 + lane * 4]);
    float ax = wself * hv.x, ay = wself * hv.y, az = wself * hv.z, aw = wself * hv.w;
    int j = start;
    for (; j + 4 <= end; j += 4) {
        int s0 = col[j], s1 = col[j + 1], s2 = col[j + 2], s3 = col[j + 3];
        float w0 = __expf(LRELU(asrc[s0] + ad) - m);
        float w1 = __expf(LRELU(asrc[s1] + ad) - m);
        float w2 = __expf(LRELU(asrc[s2] + ad) - m);
        float w3 = __expf(LRELU(asrc[s3] + ad) - m);
        denom += w0 + w1 + w2 + w3;
        float4 h0 = bf4_to_f32(*(const ushort4*)&hb[(size_t)s0 * 256 + lane * 4]);
        float4 h1 = bf4_to_f32(*(const ushort4*)&hb[(size_t)s1 * 256 + lane * 4]);
        float4 h2 = bf4_to_f32(*(const ushort4*)&hb[(size_t)s2 * 256 + lane * 4]);
        float4 h3 = bf4_to_f32(*(const ushort4*)&hb[(size_t)s3 * 256 + lane * 4]);
        ax = fmaf(w0, h0.x, fmaf(w1, h1.x, fmaf(w2, h2.x, fmaf(w3, h3.x, ax))));
        ay = fmaf(w0, h0.y, fmaf(w1, h1.y, fmaf(w2, h2.y, fmaf(w3, h3.y, ay))));
        az = fmaf(w0, h0.z, fmaf(w1, h1.z, fmaf(w2, h2.z, fmaf(w3, h3.z, az))));
        aw = fmaf(w0, h0.w, fmaf(w1, h1.w, fmaf(w2, h2.w, fmaf(w3, h3.w, aw))));
    }
    for (; j < end; j++) {
        int s = col[j];
        float wgt = __expf(LRELU(asrc[s] + ad) - m);
        denom += wgt;
        float4 hx = bf4_to_f32(*(const ushort4*)&hb[(size_t)s * 256 + lane * 4]);
        ax = fmaf(wgt, hx.x, ax); ay = fmaf(wgt, hx.y, ay);
        az = fmaf(wgt, hx.z, az); aw = fmaf(wgt, hx.w, aw);
    }
    float inv = 1.0f / (denom + 1e-16f);
    float4 bv = *(const float4*)&bias[lane * 4];
    float ox = fmaxf(fmaf(ax, inv, bv.x), 0.0f);
    float oy = fmaxf(fmaf(ay, inv, bv.y), 0.0f);
    float oz = fmaxf(fmaf(az, inv, bv.z), 0.0f);
    float ow = fmaxf(fmaf(aw, inv, bv.w), 0.0f);
    if (outf) {
        float4 o = make_float4(ox, oy, oz, ow);
        *(float4*)&outf[(size_t)node * 256 + lane * 4] = o;
    }
    if (outh) {
        float of[4] = {ox, oy, oz, ow};
        unsigned long long ph = 0, pl = 0;
#pragma unroll
        for (int e = 0; e < 4; e++) {
            unsigned u = __builtin_bit_cast(unsigned, of[e]);
            unsigned t = u + 0x7FFF + ((u >> 16) & 1);
            float hf = __builtin_bit_cast(float, t & 0xFFFF0000u);
            float fl = of[e] - hf;
            unsigned u2 = __builtin_bit_cast(unsigned, fl);
            unsigned t2 = u2 + 0x7FFF + ((u2 >> 16) & 1);
            ph |= ((unsigned long long)(t >> 16)) << (16 * e);
            pl |= ((unsigned long long)(t2 >> 16)) << (16 * e);
        }
        *(unsigned long long*)&outh[(size_t)node * 256 + lane * 4] = ph;
        *(unsigned long long*)&outl[(size_t)node * 256 + lane * 4] = pl;
    }
    if (gatep) {
        float4 gv = *(const float4*)&gw[lane * 4];
        float s = ox * gv.x + oy * gv.y + oz * gv.z + ow * gv.w;
#pragma unroll
        for (int off = 32; off; off >>= 1) s += __shfl_xor(s, off);
        if (lane == 0) gatep[node] = s + gb[0];
    }
}

// ---------------- global attention
__global__ __launch_bounds__(256) void k_pmax(const float* __restrict__ gate, int N,
                                              float* __restrict__ pmax) {
    __shared__ float red[256];
    int tid = threadIdx.x;
    float m = -3.0e38f;
    for (int i = blockIdx.x * 256 + tid; i < N; i += gridDim.x * 256) m = fmaxf(m, gate[i]);
    red[tid] = m;
    __syncthreads();
    for (int off = 128; off; off >>= 1) {
        if (tid < off) red[tid] = fmaxf(red[tid], red[tid + off]);
        __syncthreads();
    }
    if (tid == 0) pmax[blockIdx.x] = red[0];
}

__global__ __launch_bounds__(256) void k_gmid(const float* __restrict__ pmax, int nb,
                                              float* __restrict__ scal,
                                              float* __restrict__ gout) {
    __shared__ float red[256];
    int tid = threadIdx.x;
    red[tid] = (tid < nb) ? pmax[tid] : -3.0e38f;
    __syncthreads();
    for (int off = 128; off; off >>= 1) {
        if (tid < off) red[tid] = fmaxf(red[tid], red[tid + off]);
        __syncthreads();
    }
    if (tid == 0) { scal[0] = red[0]; scal[1] = 0.0f; }
    gout[tid] = 0.0f;
}

__global__ __launch_bounds__(256) void k_gout(const float* __restrict__ h,
                                              const float* __restrict__ gate,
                                              float* __restrict__ scal_rw,
                                              float* __restrict__ gout, int N) {
    int f = threadIdx.x;
    float gmax = scal_rw[0];
    float acc = 0.0f, sumw = 0.0f;
    for (int i = blockIdx.x; i < N; i += gridDim.x) {
        float w = __expf(gate[i] - gmax);
        acc = fmaf(w, h[(size_t)i * 256 + f], acc);
        sumw += w;
    }
    atomicAdd(&gout[f], acc);
    if (f == 0) atomicAdd(&scal_rw[1], sumw);
}

__global__ __launch_bounds__(256) void k_final(const float* __restrict__ gout,
                                               const float* __restrict__ scal,
                                               float* __restrict__ out) {
    int f = threadIdx.x;
    out[f] = gout[f] / scal[1];
}

extern "C" void kernel_launch(void* const* d_in, const int* in_sizes, int n_in,
                              void* d_out, int out_size, void* d_ws, size_t ws_size,
                              hipStream_t stream) {
    const float* x   = (const float*)d_in[0];
    const int*   ei  = (const int*)d_in[1];
    const float* W1  = (const float*)d_in[2];
    const float* b1  = (const float*)d_in[3];
    const float* as1 = (const float*)d_in[4];
    const float* ad1 = (const float*)d_in[5];
    const float* W2  = (const float*)d_in[6];
    const float* b2  = (const float*)d_in[7];
    const float* as2 = (const float*)d_in[8];
    const float* ad2 = (const float*)d_in[9];
    const float* gw  = (const float*)d_in[10];
    const float* gb  = (const float*)d_in[11];
    float* out = (float*)d_out;

    const int N = in_sizes[0] / 768;   // 50000
    const int E = in_sizes[1] / 2;     // 800000
    const int Mpad = (N + 127) & ~127; // 50048
    const int* srcA = ei;
    const int* dstA = ei + E;

    char* w = (char*)d_ws;
    auto alloc = [&](size_t bytes) -> void* {
        void* p = (void*)w;
        w += (bytes + 255) & ~(size_t)255;
        return p;
    };
    unsigned short* bufHb = (unsigned short*)alloc((size_t)N * 256 * 2);  // bf16 h table
    unsigned short* X2h = (unsigned short*)alloc((size_t)Mpad * 256 * 2);
    unsigned short* X2l = (unsigned short*)alloc((size_t)Mpad * 256 * 2);
    float* bufX = (float*)X2h;  // alias: X2 planes dead after GEMM2; k_edge l2 writes after
    float* asrc   = (float*)alloc((size_t)N * 4);
    float* adst   = (float*)alloc((size_t)N * 4);
    float* gate   = (float*)alloc((size_t)N * 4);
    int*   counts = (int*)alloc((size_t)N * 4);
    int*   rowptr = (int*)alloc((size_t)(N + 1) * 4);
    int*   cursor = (int*)alloc((size_t)N * 4);
    int*   colbuf = (int*)alloc((size_t)E * 4);
    int*   psum   = (int*)alloc(256 * 4);
    float* pmax   = (float*)alloc(256 * 4);
    float* scal   = (float*)alloc(8 * 4);
    float* gout   = (float*)alloc(256 * 4);
    unsigned short* BT1h = (unsigned short*)alloc((size_t)256 * 768 * 2);
    unsigned short* BT1l = (unsigned short*)alloc((size_t)256 * 768 * 2);
    unsigned short* BT2h = (unsigned short*)alloc((size_t)256 * 256 * 2);
    unsigned short* BT2l = (unsigned short*)alloc((size_t)256 * 256 * 2);

    const int eb  = (E + 255) / 256;
    const int nb4 = (N + 3) / 4;
    const int nb  = (N + 255) / 256;
    const dim3 gg(Mpad / 128, 2);

    // weight split/transpose
    k_convB<<<768, 256, 0, stream>>>(W1, BT1h, BT1l, 768);
    k_convB<<<256, 256, 0, stream>>>(W2, BT2h, BT2l, 256);

    // CSR by dst
    (void)hipMemsetAsync(counts, 0, (size_t)N * 4, stream);
    k_degree<<<eb, 256, 0, stream>>>(dstA, counts, E);
    k_part<<<nb, 256, 0, stream>>>(counts, psum, N);
    k_scan_part<<<1, 256, 0, stream>>>(psum, nb, rowptr + N);
    k_rowptr<<<nb, 256, 0, stream>>>(counts, psum, rowptr, cursor, N);
    k_scatter<<<eb, 256, 0, stream>>>(srcA, dstA, cursor, colbuf, E);

    // layer 1
    (void)hipMemsetAsync(asrc, 0, (size_t)N * 4, stream);
    (void)hipMemsetAsync(adst, 0, (size_t)N * 4, stream);
    k_gemm_f32A<<<gg, 256, 0, stream>>>(x, BT1h, BT1l, bufHb, asrc, adst, as1, ad1, N, 768);
    k_edge<<<nb4, 256, 0, stream>>>(bufHb, asrc, adst, rowptr, colbuf, b1,
                                    nullptr, X2h, X2l, nullptr, nullptr, nullptr, N);

    // layer 2
    (void)hipMemsetAsync(asrc, 0, (size_t)N * 4, stream);
    (void)hipMemsetAsync(adst, 0, (size_t)N * 4, stream);
    k_gemm_bf16A<<<gg, 256, 0, stream>>>(X2h, X2l, BT2h, BT2l, bufHb, asrc, adst, as2, ad2, N, 256);
    k_edge<<<nb4, 256, 0, stream>>>(bufHb, asrc, adst, rowptr, colbuf, b2,
                                    bufX, nullptr, nullptr, gw, gb, gate, N);

    // global attention
    k_pmax<<<64, 256, 0, stream>>>(gate, N, pmax);
    k_gmid<<<1, 256, 0, stream>>>(pmax, 64, scal, gout);
    k_gout<<<256, 256, 0, stream>>>(bufX, gate, scal, gout, N);
    k_final<<<1, 256, 0, stream>>>(gout, scal, out);
}